// Round 5
// baseline (311.468 us; speedup 1.0000x reference)
//
#include <hip/hip_runtime.h>
#include <hip/hip_bf16.h>
#include <math.h>

typedef unsigned short u16;
typedef unsigned int   u32;
typedef unsigned char  u8;

#define H128 128
#define SENT -4.0f   // all sims are unit-vector dots, |dot| <= ~1.02

__device__ __forceinline__ float bf2f(u16 v){
    u32 u = ((u32)v) << 16;
    return __uint_as_float(u);
}
__device__ __forceinline__ u16 f2bf(float x){
    u32 u = __float_as_uint(x);
    u32 r = (u + 0x7fffu + ((u >> 16) & 1u)) >> 16;
    return (u16)r;
}
__device__ __forceinline__ void unpack8(uint4 v, float* f){
    f[0] = bf2f((u16)(v.x & 0xffff)); f[1] = bf2f((u16)(v.x >> 16));
    f[2] = bf2f((u16)(v.y & 0xffff)); f[3] = bf2f((u16)(v.y >> 16));
    f[4] = bf2f((u16)(v.z & 0xffff)); f[5] = bf2f((u16)(v.z >> 16));
    f[6] = bf2f((u16)(v.w & 0xffff)); f[7] = bf2f((u16)(v.w >> 16));
}
// dual-dtype input loaders: F==1 -> float32 data, F==0 -> bf16 data
__device__ __forceinline__ float ld1(const void* p, size_t i, int F){
    return F ? ((const float*)p)[i] : bf2f(((const u16*)p)[i]);
}
__device__ __forceinline__ void ld8(const void* p, size_t i, int F, float* f){
    if (F){
        const float* fp = (const float*)p + i;
        float4 a = *(const float4*)fp;
        float4 b = *(const float4*)(fp + 4);
        f[0]=a.x; f[1]=a.y; f[2]=a.z; f[3]=a.w;
        f[4]=b.x; f[5]=b.y; f[6]=b.z; f[7]=b.w;
    } else {
        uint4 v = *(const uint4*)((const u16*)p + i);
        unpack8(v, f);
    }
}
// clamp that also sanitizes NaN (fmaxf(NaN,lo)=lo per IEEE)
__device__ __forceinline__ float clampf(float x, float lo, float hi){
    return fminf(fmaxf(x, lo), hi);
}

// ---------------- K0: once — dtype detect, accumulators, lang_num decode ----------------
__global__ void k_init(const int* __restrict__ lang_raw, const void* __restrict__ pred_size,
                       int* __restrict__ lni, float* __restrict__ accf,
                       int* __restrict__ flagp, int B)
{
    if (threadIdx.x == 0 && blockIdx.x == 0){
        accf[0] = 0.f; accf[1] = 0.f;
        // dtype detect: pred_size values in [0.2,1.5]. As bf16, every u16 code is in
        // [0x3000,0x4100). As f32, the 64 low-halves are ~uniform (only ~6% in range).
        const u16* ps = (const u16*)pred_size;
        int inr = 0;
        for (int i = 0; i < 128; i++){
            u16 v = ps[i];
            if (v >= 0x3000 && v < 0x4100) inr++;
        }
        *flagp = (inr >= 120) ? 0 : 1;   // 0 = bf16, 1 = f32
        // lang_num may arrive int64 (high words zero, values in [1,L]) or int32
        bool is64 = (B >= 8) && lang_raw[1] == 0 && lang_raw[3] == 0 &&
                    lang_raw[5] == 0 && lang_raw[7] == 0;
        for (int i = 0; i < B; i++) lni[i] = is64 ? lang_raw[2 * i] : lang_raw[i];
    }
}

// ---------------- K1 (per chunk): objectness mask + count ----------------
__global__ void __launch_bounds__(256) k_meta(
        const void* __restrict__ obj, const int* __restrict__ Fp,
        u8* __restrict__ mask, float* __restrict__ cnt, int* __restrict__ needcnt,
        int b0, int P)
{
    const int F = *Fp;
    int b = blockIdx.x, tid = threadIdx.x;
    float c = 0.f;
    for (int p = tid; p < P; p += 256){
        size_t base = ((size_t)(b0 + b) * P + p) * 2;
        float s0 = ld1(obj, base, F);
        float s1 = ld1(obj, base + 1, F);
        u8 m = (s1 > s0) ? 1 : 0;          // argmax==1 (tie -> index 0)
        mask[(size_t)b * P + p] = m;
        c += (float)m;
    }
    __shared__ float red[256];
    red[tid] = c; __syncthreads();
    for (int st = 128; st > 0; st >>= 1){
        if (tid < st) red[tid] += red[tid + st];
        __syncthreads();
    }
    if (tid == 0){ cnt[b] = red[0]; needcnt[b] = 0; }
}

// ---------------- K2 (per chunk): AABB IoU -> tgt ----------------
__global__ void __launch_bounds__(256) k_tgt(
        const void* __restrict__ gtc, const void* __restrict__ gts,
        const void* __restrict__ pc_, const void* __restrict__ ps_,
        const int* __restrict__ Fp, const u8* __restrict__ mask,
        u8* __restrict__ tgt, float* __restrict__ tcnt, int b0, int P, int L)
{
    const int F = *Fp;
    int blk = blockIdx.x, b = blk / L, l = blk % L, tid = threadIdx.x;
    float gmin[3], gmax[3], gs[3];
    for (int i = 0; i < 3; i++){
        size_t gi = ((size_t)(b0 + b) * L + l) * 3 + i;
        float gc = ld1(gtc, gi, F);
        gs[i] = ld1(gts, gi, F) + 0.01f;
        gmin[i] = gc - 0.5f * gs[i];
        gmax[i] = gc + 0.5f * gs[i];
    }
    float volg = gs[0] * gs[1] * gs[2];
    float c = 0.f;
    for (int p = tid; p < P; p += 256){
        size_t base = ((size_t)(b0 + b) * P + p) * 3;
        float inter = 1.f, volp = 1.f;
        for (int i = 0; i < 3; i++){
            float pcv = ld1(pc_, base + i, F);
            float psv = ld1(ps_, base + i, F);
            float mn = fmaxf(gmin[i], pcv - 0.5f * psv);
            float mx = fminf(gmax[i], pcv + 0.5f * psv);
            inter *= fmaxf(mx - mn, 0.f);
            volp  *= psv;
        }
        float iou = inter / (volg + volp - inter + 1e-7f);
        u8 t = (iou > 0.25f && mask[(size_t)b * P + p]) ? 1 : 0;
        tgt[((size_t)b * L + l) * P + p] = t;
        c += (float)t;
    }
    __shared__ float red[256];
    red[tid] = c; __syncthreads();
    for (int st = 128; st > 0; st >>= 1){
        if (tid < st) red[tid] += red[tid + st];
        __syncthreads();
    }
    if (tid == 0) tcnt[b * L + l] = red[0];
}

// ---------------- K3 (per chunk): compact rows needing LSE_q; zero lse ----------------
__global__ void __launch_bounds__(256) k_need(
        const u8* __restrict__ tgt, int* __restrict__ needcnt,
        int* __restrict__ needlist, float* __restrict__ lse, int P, int L)
{
    int b = blockIdx.x;
    for (int p = threadIdx.x; p < P; p += 256){
        lse[(size_t)b * P + p] = 0.f;
        bool any = false;
        for (int l = 0; l < L; l++) any |= (tgt[((size_t)b * L + l) * P + p] != 0);
        if (any){
            int pos = atomicAdd(&needcnt[b], 1);
            needlist[(size_t)b * P + pos] = p;
        }
    }
}

// ---------------- K4 (per chunk): projections + normalize ----------------
__global__ void __launch_bounds__(128) k_proj(
        const void* __restrict__ bbox, const void* __restrict__ lang,
        const void* __restrict__ Wp, const void* __restrict__ Wpi, const void* __restrict__ Wt,
        const int* __restrict__ Fp,
        u16* __restrict__ boxl, u16* __restrict__ boxi, float* __restrict__ text,
        int nb1, int rowoff_bp, int rowoff_t, int nrows_bp, int nrows_t)
{
    const int F = *Fp;
    int blk = blockIdx.x, tid = threadIdx.x;
    const void *X, *W; u16* outb = 0; float* outf = 0; int row0, nrows, rowoff;
    if (blk < nb1)          { X = bbox; W = Wp;  outb = boxl; row0 = blk * 32;             nrows = nrows_bp; rowoff = rowoff_bp; }
    else if (blk < 2 * nb1) { X = bbox; W = Wpi; outb = boxi; row0 = (blk - nb1) * 32;     nrows = nrows_bp; rowoff = rowoff_bp; }
    else                    { X = lang; W = Wt;  outf = text; row0 = (blk - 2 * nb1) * 32; nrows = nrows_t;  rowoff = rowoff_t; }

    __shared__ float xs[32][H128];
    for (int k = 0; k < 4; k++){
        int e = tid + k * 128;            // 512 chunks of 8 elems
        int r = e >> 4, c8 = (e & 15) * 8;
        int row = row0 + r;
        float f[8];
        if (row < nrows){
            ld8(X, (size_t)(rowoff + row) * H128 + c8, F, f);
        } else {
            for (int j = 0; j < 8; j++) f[j] = 0.f;
        }
        #pragma unroll
        for (int j = 0; j < 8; j++) xs[r][c8 + j] = f[j];
    }
    __syncthreads();

    int g  = tid >> 5;    // row group g: rows g*8 .. g*8+7
    int ht = tid & 31;    // h = ht + 32*h4
    float acc[8][4];
    #pragma unroll
    for (int r = 0; r < 8; r++)
        #pragma unroll
        for (int h4 = 0; h4 < 4; h4++) acc[r][h4] = 0.f;

    for (int c = 0; c < 16; c++){
        float wf[4][8];
        #pragma unroll
        for (int h4 = 0; h4 < 4; h4++)
            ld8(W, (size_t)(ht + h4 * 32) * H128 + c * 8, F, wf[h4]);
        #pragma unroll
        for (int r = 0; r < 8; r++){
            float xv[8];
            #pragma unroll
            for (int j = 0; j < 8; j++) xv[j] = xs[g * 8 + r][c * 8 + j];
            #pragma unroll
            for (int h4 = 0; h4 < 4; h4++)
                #pragma unroll
                for (int j = 0; j < 8; j++) acc[r][h4] += xv[j] * wf[h4][j];
        }
    }
    #pragma unroll
    for (int r = 0; r < 8; r++){
        #pragma unroll
        for (int h4 = 0; h4 < 4; h4++) acc[r][h4] = clampf(acc[r][h4], -1e4f, 1e4f);
        float t = acc[r][0]*acc[r][0] + acc[r][1]*acc[r][1] +
                  acc[r][2]*acc[r][2] + acc[r][3]*acc[r][3];
        for (int off = 16; off > 0; off >>= 1) t += __shfl_xor(t, off);
        float rn = 1.0f / fmaxf(sqrtf(t), 1e-12f);
        int row = row0 + g * 8 + r;
        if (row < nrows){
            #pragma unroll
            for (int h4 = 0; h4 < 4; h4++){
                float o = acc[r][h4] * rn;
                size_t oi = (size_t)row * H128 + ht + h4 * 32;
                if (outb) outb[oi] = f2bf(o); else outf[oi] = o;
            }
        }
    }
}

// ---------------- K5 (per chunk): lang NCE per (b,l) — exact two-pass ----------------
__global__ void __launch_bounds__(256) k_lang(
        const float* __restrict__ text, const u16* __restrict__ boxl,
        const u8* __restrict__ mask, const u8* __restrict__ tgt,
        const float* __restrict__ cnt, const float* __restrict__ tcnt,
        const int* __restrict__ lni, float* __restrict__ accf,
        int b0, int P, int L)
{
    int blk = blockIdx.x, b = blk / L, l = blk % L, tid = threadIdx.x;
    if (l >= lni[b0 + b]) return;
    float t = tcnt[b * L + l];
    if (t <= 0.f) return;
    float cnt1 = fmaxf(cnt[b], 1.f);

    __shared__ float tx[H128];
    if (tid < H128) tx[tid] = text[((size_t)b * L + l) * H128 + tid];
    __syncthreads();

    float dots[8]; u8 act[8], tg[8];
    int nj = 0;
    for (int p = tid; p < P && nj < 8; p += 256){
        u8 a = mask[(size_t)b * P + p];
        float dot = SENT;
        if (a){
            const u16* row = &boxl[((size_t)b * P + p) * H128];
            dot = 0.f;
            for (int c = 0; c < 16; c++){
                uint4 v = *(const uint4*)&row[c * 8];
                float f[8]; unpack8(v, f);
                float4 t0 = *(const float4*)&tx[c * 8];
                float4 t1 = *(const float4*)&tx[c * 8 + 4];
                dot += f[0]*t0.x + f[1]*t0.y + f[2]*t0.z + f[3]*t0.w
                     + f[4]*t1.x + f[5]*t1.y + f[6]*t1.z + f[7]*t1.w;
            }
            dot = clampf(dot, -3.f, 3.f);   // legit |dot|<=~1.02; sanitizes garbage
        }
        dots[nj] = dot; act[nj] = a;
        tg[nj] = tgt[((size_t)b * L + l) * P + p];
        nj++;
    }

    __shared__ float red[256], r2[256];
    float Mloc = SENT;
    for (int j = 0; j < nj; j++) Mloc = fmaxf(Mloc, dots[j]);
    red[tid] = Mloc; __syncthreads();
    for (int st = 128; st > 0; st >>= 1){
        if (tid < st) red[tid] = fmaxf(red[tid], red[tid + st]);
        __syncthreads();
    }
    float M = red[0];
    __syncthreads();
    float sloc = 0.f, Sloc = 0.f;
    for (int j = 0; j < nj; j++){
        if (act[j]) sloc += __expf(dots[j] - M);
        if (tg[j])  Sloc += dots[j];
    }
    red[tid] = sloc; r2[tid] = Sloc; __syncthreads();
    for (int st = 128; st > 0; st >>= 1){
        if (tid < st){ red[tid] += red[tid + st]; r2[tid] += r2[tid + st]; }
        __syncthreads();
    }
    if (tid == 0){
        float LSE = M + logf(red[0]);   // red[0] >= 1
        atomicAdd(&accf[0], clampf(0.5f * (t * LSE - r2[0]) / cnt1, -1e5f, 1e5f));
    }
}

// ---------------- K6 (per chunk): LSE over q for needed rows — exact two-pass ----------------
// Requires P == 4*256 (P=1024): every q handled once, all dots in registers.
__global__ void __launch_bounds__(256) k_lse(
        const u16* __restrict__ boxi, const u8* __restrict__ mask,
        const int* __restrict__ needcnt, const int* __restrict__ needlist,
        float* __restrict__ lse, int P, int tilesPerB)
{
    int b = blockIdx.x / tilesPerB;
    int i0 = (blockIdx.x % tilesPerB) * 16;
    int ncnt = needcnt[b];
    if (i0 >= ncnt) return;
    int tid = threadIdx.x;

    __shared__ int sidx[16];
    __shared__ float pls[16][H128];
    if (tid < 16){
        int i = i0 + tid;
        sidx[tid] = needlist[(size_t)b * P + ((i < ncnt) ? i : i0)];
    }
    __syncthreads();
    {
        int r = tid >> 4, c8 = (tid & 15) * 8;
        uint4 v = *(const uint4*)&boxi[((size_t)b * P + sidx[r]) * H128 + c8];
        float f[8]; unpack8(v, f);
        #pragma unroll
        for (int j = 0; j < 8; j++) pls[r][c8 + j] = f[j];
    }
    __syncthreads();

    int q0 = tid * 4;
    u8 mk[4];
    #pragma unroll
    for (int j = 0; j < 4; j++) mk[j] = mask[(size_t)b * P + q0 + j];

    float acc[16][4];
    #pragma unroll
    for (int r = 0; r < 16; r++)
        #pragma unroll
        for (int j = 0; j < 4; j++) acc[r][j] = 0.f;

    const u16* qb = &boxi[((size_t)b * P + q0) * H128];
    for (int c = 0; c < 16; c++){
        uint4 v0 = *(const uint4*)&qb[0 * H128 + c * 8];
        uint4 v1 = *(const uint4*)&qb[1 * H128 + c * 8];
        uint4 v2 = *(const uint4*)&qb[2 * H128 + c * 8];
        uint4 v3 = *(const uint4*)&qb[3 * H128 + c * 8];
        float q0f[8], q1f[8], q2f[8], q3f[8];
        unpack8(v0, q0f); unpack8(v1, q1f); unpack8(v2, q2f); unpack8(v3, q3f);
        #pragma unroll
        for (int r = 0; r < 16; r++){
            #pragma unroll
            for (int j = 0; j < 8; j++){
                float pv = pls[r][c * 8 + j];
                acc[r][0] += pv * q0f[j];
                acc[r][1] += pv * q1f[j];
                acc[r][2] += pv * q2f[j];
                acc[r][3] += pv * q3f[j];
            }
        }
    }
    #pragma unroll
    for (int r = 0; r < 16; r++)
        #pragma unroll
        for (int j = 0; j < 4; j++) acc[r][j] = clampf(acc[r][j], -3.f, 3.f);

    int lane = tid & 63, wid = tid >> 6;
    __shared__ float wred[4][16];
    __shared__ float Mx[16];
    #pragma unroll
    for (int r = 0; r < 16; r++){
        float m = SENT;
        #pragma unroll
        for (int j = 0; j < 4; j++) if (mk[j]) m = fmaxf(m, acc[r][j]);
        for (int off = 32; off > 0; off >>= 1) m = fmaxf(m, __shfl_xor(m, off));
        if (lane == 0) wred[wid][r] = m;
    }
    __syncthreads();
    if (tid < 16)
        Mx[tid] = fmaxf(fmaxf(wred[0][tid], wred[1][tid]),
                        fmaxf(wred[2][tid], wred[3][tid]));
    __syncthreads();
    #pragma unroll
    for (int r = 0; r < 16; r++){
        float Mr = Mx[r];
        float s = 0.f;
        #pragma unroll
        for (int j = 0; j < 4; j++) if (mk[j]) s += __expf(acc[r][j] - Mr);
        for (int off = 32; off > 0; off >>= 1) s += __shfl_xor(s, off);
        if (lane == 0) wred[wid][r] = s;
    }
    __syncthreads();
    if (tid < 16){
        float s = wred[0][tid] + wred[1][tid] + wred[2][tid] + wred[3][tid];
        if (i0 + tid < ncnt)
            lse[(size_t)b * P + sidx[tid]] = clampf(Mx[tid] + logf(s), -20.f, 30.f);
    }
}

// ---------------- K7 (per chunk): iou NCE per (b,l) ----------------
__global__ void __launch_bounds__(256) k_iou(
        const u16* __restrict__ boxi, const u8* __restrict__ tgt,
        const float* __restrict__ lse, const float* __restrict__ cnt,
        const int* __restrict__ lni, float* __restrict__ accf, int b0, int P, int L)
{
    int blk = blockIdx.x, b = blk / L, l = blk % L, tid = threadIdx.x;
    if (l >= lni[b0 + b]) return;
    __shared__ int mem[1024];
    __shared__ int lcnt;
    __shared__ float redu[256];
    __shared__ float Ufin;
    if (tid == 0) lcnt = 0;
    __syncthreads();
    for (int p = tid; p < P; p += 256)
        if (tgt[((size_t)b * L + l) * P + p])
            mem[atomicAdd(&lcnt, 1)] = p;
    __syncthreads();
    int t = lcnt;
    if (t == 0) return;

    float U = 0.f;
    for (int i = tid; i < t; i += 256) U += lse[(size_t)b * P + mem[i]];
    redu[tid] = U; __syncthreads();
    for (int st = 128; st > 0; st >>= 1){
        if (tid < st) redu[tid] += redu[tid + st];
        __syncthreads();
    }
    if (tid == 0) Ufin = redu[0];
    __syncthreads();

    float vh = 0.f;
    if (tid < H128)
        for (int i = 0; i < t; i++)
            vh += bf2f(boxi[((size_t)b * P + mem[i]) * H128 + tid]);
    redu[tid] = (tid < H128) ? vh * vh : 0.f;
    __syncthreads();
    for (int st = 128; st > 0; st >>= 1){
        if (tid < st) redu[tid] += redu[tid + st];
        __syncthreads();
    }
    if (tid == 0){
        float c1 = fmaxf(cnt[b], 1.f);
        atomicAdd(&accf[1], clampf(((float)t * Ufin - redu[0]) / (c1 * c1), -1e5f, 1e5f));
    }
}

// ---------------- K8: finalize (output dtype follows detected input dtype) ----------------
__global__ void k_fin(const float* __restrict__ accf, const int* __restrict__ flagp,
                      void* __restrict__ out, float invB)
{
    if (threadIdx.x == 0 && blockIdx.x == 0){
        float a = clampf(accf[0] * invB, -1e6f, 1e6f);
        float b = clampf(accf[1] * invB, -1e6f, 1e6f);
        if (*flagp){
            ((float*)out)[0] = a; ((float*)out)[1] = b;
        } else {
            ((u16*)out)[0] = f2bf(a); ((u16*)out)[1] = f2bf(b);
        }
    }
}

extern "C" void kernel_launch(void* const* d_in, const int* in_sizes, int n_in,
                              void* d_out, int out_size, void* d_ws, size_t ws_size,
                              hipStream_t stream)
{
    const void* pred_center = d_in[0];
    const void* pred_size   = d_in[1];
    const void* bbox        = d_in[2];
    const void* gtc         = d_in[3];
    const void* gts         = d_in[4];
    const void* lang        = d_in[5];
    const void* obj         = d_in[6];
    const void* Wt          = d_in[7];
    const void* Wp          = d_in[8];
    const void* Wpi         = d_in[9];
    const int*  lang_raw    = (const int*)d_in[10];

    int B = in_sizes[10];
    int P = in_sizes[0] / (3 * B);
    int L = in_sizes[3] / (3 * B);
    (void)n_in; (void)out_size;

    // ---- fixed area ----
    char* w = (char*)d_ws;
    float* accf  = (float*)w;            // [0..1] losses
    int*   flagp = (int*)(w + 64);       // dtype flag
    int*   lni   = (int*)(w + 256);      // <= 256 B
    char*  chunk_base = w + 512;
    size_t chunk_avail = (ws_size > 512) ? ws_size - 512 : 0;

    size_t per_b = (size_t)P + (size_t)P * 4 + 8 + (size_t)L * 4
                 + (size_t)L * P + (size_t)P * 4
                 + (size_t)P * H128 * 2 * 2 + (size_t)L * H128 * 4;
    size_t slop = 12 * 256;
    int C = B;
    if ((size_t)B * per_b + slop > chunk_avail){
        size_t av = (chunk_avail > slop) ? chunk_avail - slop : 0;
        C = (int)(av / per_b);
        if (C < 1) C = 1;
        if (C > B) C = B;
    }

    k_init<<<1, 64, 0, stream>>>(lang_raw, pred_size, lni, accf, flagp, B);

    for (int b0 = 0; b0 < B; b0 += C){
        int c = (B - b0 < C) ? (B - b0) : C;

        size_t off = 0;
        auto carve = [&](size_t bytes) -> void* {
            void* p = chunk_base + off;
            off = (off + bytes + 255) & ~(size_t)255;
            return p;
        };
        u8*    mask     = (u8*)   carve((size_t)c * P);
        float* cnt      = (float*)carve((size_t)c * 4);
        int*   needcnt  = (int*)  carve((size_t)c * 4);
        float* tcnt     = (float*)carve((size_t)c * L * 4);
        u8*    tgtb     = (u8*)   carve((size_t)c * L * P);
        int*   needlist = (int*)  carve((size_t)c * P * 4);
        float* lse      = (float*)carve((size_t)c * P * 4);
        u16*   boxl     = (u16*)  carve((size_t)c * P * H128 * 2);
        u16*   boxi     = (u16*)  carve((size_t)c * P * H128 * 2);
        float* text     = (float*)carve((size_t)c * L * H128 * 4);

        k_meta<<<c, 256, 0, stream>>>(obj, flagp, mask, cnt, needcnt, b0, P);
        k_tgt <<<c * L, 256, 0, stream>>>(gtc, gts, pred_center, pred_size, flagp,
                                          mask, tgtb, tcnt, b0, P, L);
        k_need<<<c, 256, 0, stream>>>(tgtb, needcnt, needlist, lse, P, L);
        int nb1 = (c * P) / 32;
        int nbt = (c * L + 31) / 32;
        k_proj<<<2 * nb1 + nbt, 128, 0, stream>>>(bbox, lang, Wp, Wpi, Wt, flagp,
                                                  boxl, boxi, text, nb1,
                                                  b0 * P, b0 * L, c * P, c * L);
        k_lang<<<c * L, 256, 0, stream>>>(text, boxl, mask, tgtb, cnt, tcnt, lni, accf, b0, P, L);
        k_lse <<<c * (P / 16), 256, 0, stream>>>(boxi, mask, needcnt, needlist, lse, P, P / 16);
        k_iou <<<c * L, 256, 0, stream>>>(boxi, tgtb, lse, cnt, lni, accf, b0, P, L);
    }

    k_fin<<<1, 64, 0, stream>>>(accf, flagp, d_out, 1.0f / (float)B);
}

// Round 6
// 234.562 us; speedup vs baseline: 1.3279x; 1.3279x over previous
//
#include <hip/hip_runtime.h>
#include <hip/hip_bf16.h>
#include <math.h>

typedef unsigned short u16;
typedef unsigned int   u32;
typedef unsigned char  u8;

typedef __attribute__((ext_vector_type(8))) short short8_t;
typedef __attribute__((ext_vector_type(4))) float f32x4_t;

#define H128 128

__device__ __forceinline__ float bf2f(u16 v){
    u32 u = ((u32)v) << 16;
    return __uint_as_float(u);
}
__device__ __forceinline__ u16 f2bf(float x){
    u32 u = __float_as_uint(x);
    u32 r = (u + 0x7fffu + ((u >> 16) & 1u)) >> 16;
    return (u16)r;
}
__device__ __forceinline__ void unpack8(uint4 v, float* f){
    f[0] = bf2f((u16)(v.x & 0xffff)); f[1] = bf2f((u16)(v.x >> 16));
    f[2] = bf2f((u16)(v.y & 0xffff)); f[3] = bf2f((u16)(v.y >> 16));
    f[4] = bf2f((u16)(v.z & 0xffff)); f[5] = bf2f((u16)(v.z >> 16));
    f[6] = bf2f((u16)(v.w & 0xffff)); f[7] = bf2f((u16)(v.w >> 16));
}
// dual-dtype input loaders: F==1 -> float32 data, F==0 -> bf16 data
__device__ __forceinline__ float ld1(const void* p, size_t i, int F){
    return F ? ((const float*)p)[i] : bf2f(((const u16*)p)[i]);
}
__device__ __forceinline__ void ld8(const void* p, size_t i, int F, float* f){
    if (F){
        const float* fp = (const float*)p + i;
        float4 a = *(const float4*)fp;
        float4 b = *(const float4*)(fp + 4);
        f[0]=a.x; f[1]=a.y; f[2]=a.z; f[3]=a.w;
        f[4]=b.x; f[5]=b.y; f[6]=b.z; f[7]=b.w;
    } else {
        uint4 v = *(const uint4*)((const u16*)p + i);
        unpack8(v, f);
    }
}
__device__ __forceinline__ float clampf(float x, float lo, float hi){
    return fminf(fmaxf(x, lo), hi);
}

// ---------------- K0: once — dtype detect, accumulators, lang_num decode ----------------
__global__ void k_init(const int* __restrict__ lang_raw, const void* __restrict__ pred_size,
                       int* __restrict__ lni, float* __restrict__ accf,
                       int* __restrict__ flagp, int B)
{
    if (threadIdx.x == 0 && blockIdx.x == 0){
        accf[0] = 0.f; accf[1] = 0.f;
        const u16* ps = (const u16*)pred_size;
        int inr = 0;
        for (int i = 0; i < 128; i++){
            u16 v = ps[i];
            if (v >= 0x3000 && v < 0x4100) inr++;
        }
        *flagp = (inr >= 120) ? 0 : 1;   // 0 = bf16, 1 = f32
        bool is64 = (B >= 8) && lang_raw[1] == 0 && lang_raw[3] == 0 &&
                    lang_raw[5] == 0 && lang_raw[7] == 0;
        for (int i = 0; i < B; i++) lni[i] = is64 ? lang_raw[2 * i] : lang_raw[i];
    }
}

// ---------------- K1: objectness mask + count ----------------
__global__ void __launch_bounds__(256) k_meta(
        const void* __restrict__ obj, const int* __restrict__ Fp,
        u8* __restrict__ mask, float* __restrict__ cnt, int* __restrict__ needcnt,
        int b0, int P)
{
    const int F = *Fp;
    int b = blockIdx.x, tid = threadIdx.x;
    float c = 0.f;
    for (int p = tid; p < P; p += 256){
        size_t base = ((size_t)(b0 + b) * P + p) * 2;
        float s0 = ld1(obj, base, F);
        float s1 = ld1(obj, base + 1, F);
        u8 m = (s1 > s0) ? 1 : 0;
        mask[(size_t)b * P + p] = m;
        c += (float)m;
    }
    __shared__ float red[256];
    red[tid] = c; __syncthreads();
    for (int st = 128; st > 0; st >>= 1){
        if (tid < st) red[tid] += red[tid + st];
        __syncthreads();
    }
    if (tid == 0){ cnt[b] = red[0]; needcnt[b] = 0; }
}

// ---------------- K2: AABB IoU -> tgt ----------------
__global__ void __launch_bounds__(256) k_tgt(
        const void* __restrict__ gtc, const void* __restrict__ gts,
        const void* __restrict__ pc_, const void* __restrict__ ps_,
        const int* __restrict__ Fp, const u8* __restrict__ mask,
        u8* __restrict__ tgt, float* __restrict__ tcnt, int b0, int P, int L)
{
    const int F = *Fp;
    int blk = blockIdx.x, b = blk / L, l = blk % L, tid = threadIdx.x;
    float gmin[3], gmax[3], gs[3];
    for (int i = 0; i < 3; i++){
        size_t gi = ((size_t)(b0 + b) * L + l) * 3 + i;
        float gc = ld1(gtc, gi, F);
        gs[i] = ld1(gts, gi, F) + 0.01f;
        gmin[i] = gc - 0.5f * gs[i];
        gmax[i] = gc + 0.5f * gs[i];
    }
    float volg = gs[0] * gs[1] * gs[2];
    float c = 0.f;
    for (int p = tid; p < P; p += 256){
        size_t base = ((size_t)(b0 + b) * P + p) * 3;
        float inter = 1.f, volp = 1.f;
        for (int i = 0; i < 3; i++){
            float pcv = ld1(pc_, base + i, F);
            float psv = ld1(ps_, base + i, F);
            float mn = fmaxf(gmin[i], pcv - 0.5f * psv);
            float mx = fminf(gmax[i], pcv + 0.5f * psv);
            inter *= fmaxf(mx - mn, 0.f);
            volp  *= psv;
        }
        float iou = inter / (volg + volp - inter + 1e-7f);
        u8 t = (iou > 0.25f && mask[(size_t)b * P + p]) ? 1 : 0;
        tgt[((size_t)b * L + l) * P + p] = t;
        c += (float)t;
    }
    __shared__ float red[256];
    red[tid] = c; __syncthreads();
    for (int st = 128; st > 0; st >>= 1){
        if (tid < st) red[tid] += red[tid + st];
        __syncthreads();
    }
    if (tid == 0) tcnt[b * L + l] = red[0];
}

// ---------------- K3: compact rows needing LSE_q; zero lse ----------------
__global__ void __launch_bounds__(256) k_need(
        const u8* __restrict__ tgt, int* __restrict__ needcnt,
        int* __restrict__ needlist, float* __restrict__ lse, int P, int L)
{
    int b = blockIdx.x;
    for (int p = threadIdx.x; p < P; p += 256){
        lse[(size_t)b * P + p] = 0.f;
        bool any = false;
        for (int l = 0; l < L; l++) any |= (tgt[((size_t)b * L + l) * P + p] != 0);
        if (any){
            int pos = atomicAdd(&needcnt[b], 1);
            needlist[(size_t)b * P + pos] = p;
        }
    }
}

// ---------------- K4: projections + normalize — bf16 MFMA ----------------
// Block: 256 thr (4 waves). Each block computes 64 rows x 128 cols.
// LDS layout (XOR swizzle): row r, 16B-chunk c stored at chunk (c ^ (r&15)).
// A-frag: A[m=lane&15][k=quad*8+j]; B[k][n]=W[n][k] same pattern on W rows.
// C/D: col=lane&15, row=quad*4+reg.
__global__ void __launch_bounds__(256) k_proj(
        const void* __restrict__ bbox, const void* __restrict__ lang,
        const void* __restrict__ Wp, const void* __restrict__ Wpi, const void* __restrict__ Wt,
        const int* __restrict__ Fp,
        u16* __restrict__ boxl, u16* __restrict__ boxi, float* __restrict__ text,
        int nb1, int rowoff_bp, int rowoff_t, int nrows_bp, int nrows_t)
{
    const int F = *Fp;
    int blk = blockIdx.x, tid = threadIdx.x;
    const void *X, *W; u16* outb = 0; float* outf = 0; int row0, nrows, rowoff;
    if (blk < nb1)          { X = bbox; W = Wp;  outb = boxl; row0 = blk * 64;             nrows = nrows_bp; rowoff = rowoff_bp; }
    else if (blk < 2 * nb1) { X = bbox; W = Wpi; outb = boxi; row0 = (blk - nb1) * 64;     nrows = nrows_bp; rowoff = rowoff_bp; }
    else                    { X = lang; W = Wt;  outf = text; row0 = (blk - 2 * nb1) * 64; nrows = nrows_t;  rowoff = rowoff_t; }

    __shared__ __align__(16) u16 Ws[128 * H128];
    __shared__ __align__(16) u16 Xs[64 * H128];

    // stage W: 128 rows x 16 chunks = 2048 chunks
    for (int i = 0; i < 8; i++){
        int cid = tid + i * 256;
        int r = cid >> 4, cc = cid & 15;
        float f[8];
        ld8(W, (size_t)r * H128 + cc * 8, F, f);
        u16* dst = &Ws[r * H128 + ((cc ^ (r & 15)) * 8)];
        #pragma unroll
        for (int j = 0; j < 8; j++) dst[j] = f2bf(f[j]);
    }
    // stage X: 64 rows x 16 chunks = 1024 chunks
    for (int i = 0; i < 4; i++){
        int cid = tid + i * 256;
        int r = cid >> 4, cc = cid & 15;
        int row = row0 + r;
        float f[8];
        if (row < nrows){
            ld8(X, (size_t)(rowoff + row) * H128 + cc * 8, F, f);
        } else {
            #pragma unroll
            for (int j = 0; j < 8; j++) f[j] = 0.f;
        }
        u16* dst = &Xs[r * H128 + ((cc ^ (r & 15)) * 8)];
        #pragma unroll
        for (int j = 0; j < 8; j++) dst[j] = f2bf(f[j]);
    }
    __syncthreads();

    int w = tid >> 6, lane = tid & 63;
    int quad = lane >> 4, mrow = lane & 15;

    // A fragments for this wave's M-tile (rows w*16 .. w*16+15), kt = 0..3
    short8_t af[4];
    int arow = w * 16 + mrow;
    #pragma unroll
    for (int kt = 0; kt < 4; kt++){
        int chunk = kt * 4 + quad;
        af[kt] = *(const short8_t*)&Xs[arow * H128 + ((chunk ^ mrow) * 8)];
    }

    f32x4_t acc[8];
    #pragma unroll
    for (int nt = 0; nt < 8; nt++) acc[nt] = (f32x4_t){0.f, 0.f, 0.f, 0.f};

    #pragma unroll
    for (int nt = 0; nt < 8; nt++){
        int n = nt * 16 + mrow;
        #pragma unroll
        for (int kt = 0; kt < 4; kt++){
            int chunk = kt * 4 + quad;
            short8_t bf = *(const short8_t*)&Ws[n * H128 + ((chunk ^ mrow) * 8)];
            acc[nt] = __builtin_amdgcn_mfma_f32_16x16x32_bf16(af[kt], bf, acc[nt], 0, 0, 0);
        }
    }

    // row norms: lane holds rows quad*4+reg (within tile), cols nt*16+mrow
    float ss[4] = {0.f, 0.f, 0.f, 0.f};
    #pragma unroll
    for (int nt = 0; nt < 8; nt++)
        #pragma unroll
        for (int reg = 0; reg < 4; reg++) ss[reg] += acc[nt][reg] * acc[nt][reg];
    #pragma unroll
    for (int off = 1; off <= 8; off <<= 1)
        #pragma unroll
        for (int reg = 0; reg < 4; reg++) ss[reg] += __shfl_xor(ss[reg], off);
    float rn[4];
    #pragma unroll
    for (int reg = 0; reg < 4; reg++) rn[reg] = 1.0f / fmaxf(sqrtf(ss[reg]), 1e-12f);

    #pragma unroll
    for (int reg = 0; reg < 4; reg++){
        int row = row0 + w * 16 + quad * 4 + reg;
        if (row < nrows){
            #pragma unroll
            for (int nt = 0; nt < 8; nt++){
                int col = nt * 16 + mrow;
                float o = acc[nt][reg] * rn[reg];
                if (outb) outb[(size_t)row * H128 + col] = f2bf(o);
                else      outf[(size_t)row * H128 + col] = o;
            }
        }
    }
}

// ---------------- K5: lang NCE per (b,l) — single pass (|dot|<=~1.02, no max needed) ----------------
__global__ void __launch_bounds__(256) k_lang(
        const float* __restrict__ text, const u16* __restrict__ boxl,
        const u8* __restrict__ mask, const u8* __restrict__ tgt,
        const float* __restrict__ cnt, const float* __restrict__ tcnt,
        const int* __restrict__ lni, float* __restrict__ accf,
        int b0, int P, int L)
{
    int blk = blockIdx.x, b = blk / L, l = blk % L, tid = threadIdx.x;
    if (l >= lni[b0 + b]) return;
    float t = tcnt[b * L + l];
    if (t <= 0.f) return;
    float cnt1 = fmaxf(cnt[b], 1.f);

    __shared__ float tx[H128];
    if (tid < H128) tx[tid] = text[((size_t)b * L + l) * H128 + tid];
    __syncthreads();

    float s = 0.f, S = 0.f;
    for (int p = tid; p < P; p += 256){
        if (mask[(size_t)b * P + p]){
            const u16* row = &boxl[((size_t)b * P + p) * H128];
            float dot = 0.f;
            for (int c = 0; c < 16; c++){
                uint4 v = *(const uint4*)&row[c * 8];
                float f[8]; unpack8(v, f);
                float4 t0 = *(const float4*)&tx[c * 8];
                float4 t1 = *(const float4*)&tx[c * 8 + 4];
                dot += f[0]*t0.x + f[1]*t0.y + f[2]*t0.z + f[3]*t0.w
                     + f[4]*t1.x + f[5]*t1.y + f[6]*t1.z + f[7]*t1.w;
            }
            dot = clampf(dot, -3.f, 3.f);
            s += __expf(dot);
            if (tgt[((size_t)b * L + l) * P + p]) S += dot;
        }
    }
    __shared__ float red[256], r2[256];
    red[tid] = s; r2[tid] = S; __syncthreads();
    for (int st = 128; st > 0; st >>= 1){
        if (tid < st){ red[tid] += red[tid + st]; r2[tid] += r2[tid + st]; }
        __syncthreads();
    }
    if (tid == 0){
        float LSE = logf(red[0]);   // >=1 active col since t>0
        atomicAdd(&accf[0], clampf(0.5f * (t * LSE - r2[0]) / cnt1, -1e5f, 1e5f));
    }
}

// ---------------- K6: LSE over q for needed rows — bf16 MFMA, no-max sum-exp ----------------
// Block: 256 thr (4 waves). 16 gathered rows (A) x all P columns (B from boxi global).
__global__ void __launch_bounds__(256) k_lse(
        const u16* __restrict__ boxi, const u8* __restrict__ mask,
        const int* __restrict__ needcnt, const int* __restrict__ needlist,
        float* __restrict__ lse, int P, int tilesPerB)
{
    int b = blockIdx.x / tilesPerB;
    int i0 = (blockIdx.x % tilesPerB) * 16;
    int ncnt = needcnt[b];
    if (i0 >= ncnt) return;
    int tid = threadIdx.x;

    __shared__ int sidx[16];
    __shared__ __align__(16) u16 As[16 * H128];
    __shared__ float red[4][16];
    if (tid < 16){
        int i = i0 + tid;
        sidx[tid] = needlist[(size_t)b * P + ((i < ncnt) ? i : i0)];
    }
    __syncthreads();
    {   // stage A: 16 rows x 16 chunks, XOR swizzle
        int r = tid >> 4, cc = tid & 15;
        uint4 v = *(const uint4*)&boxi[((size_t)b * P + sidx[r]) * H128 + cc * 8];
        *(uint4*)&As[r * H128 + ((cc ^ r) * 8)] = v;
    }
    __syncthreads();

    int w = tid >> 6, lane = tid & 63;
    int quad = lane >> 4, mrow = lane & 15;

    short8_t af[4];
    #pragma unroll
    for (int kt = 0; kt < 4; kt++){
        int chunk = kt * 4 + quad;
        af[kt] = *(const short8_t*)&As[mrow * H128 + ((chunk ^ mrow) * 8)];
    }

    float se[4] = {0.f, 0.f, 0.f, 0.f};
    int tilesQ = P >> 4;
    for (int qt = w; qt < tilesQ; qt += 4){
        f32x4_t acc = (f32x4_t){0.f, 0.f, 0.f, 0.f};
        const u16* qbase = &boxi[((size_t)b * P + qt * 16 + mrow) * H128];
        #pragma unroll
        for (int kt = 0; kt < 4; kt++){
            short8_t bf = *(const short8_t*)&qbase[kt * 32 + quad * 8];
            acc = __builtin_amdgcn_mfma_f32_16x16x32_bf16(af[kt], bf, acc, 0, 0, 0);
        }
        // lane's 4 acc values share column qt*16+mrow (rows quad*4+reg)
        float mk = mask[(size_t)b * P + qt * 16 + mrow] ? 1.f : 0.f;
        #pragma unroll
        for (int reg = 0; reg < 4; reg++)
            se[reg] += mk * __expf(clampf(acc[reg], -3.f, 3.f));
    }
    #pragma unroll
    for (int off = 1; off <= 8; off <<= 1)
        #pragma unroll
        for (int reg = 0; reg < 4; reg++) se[reg] += __shfl_xor(se[reg], off);
    if (mrow == 0){
        #pragma unroll
        for (int reg = 0; reg < 4; reg++) red[w][quad * 4 + reg] = se[reg];
    }
    __syncthreads();
    if (tid < 16){
        float s = red[0][tid] + red[1][tid] + red[2][tid] + red[3][tid];
        if (i0 + tid < ncnt)
            lse[(size_t)b * P + sidx[tid]] = clampf(logf(s), -20.f, 30.f);
    }
}

// ---------------- K7: iou NCE per (b,l) ----------------
__global__ void __launch_bounds__(256) k_iou(
        const u16* __restrict__ boxi, const u8* __restrict__ tgt,
        const float* __restrict__ lse, const float* __restrict__ cnt,
        const int* __restrict__ lni, float* __restrict__ accf, int b0, int P, int L)
{
    int blk = blockIdx.x, b = blk / L, l = blk % L, tid = threadIdx.x;
    if (l >= lni[b0 + b]) return;
    __shared__ int mem[1024];
    __shared__ int lcnt;
    __shared__ float redu[256];
    __shared__ float Ufin;
    if (tid == 0) lcnt = 0;
    __syncthreads();
    for (int p = tid; p < P; p += 256)
        if (tgt[((size_t)b * L + l) * P + p])
            mem[atomicAdd(&lcnt, 1)] = p;
    __syncthreads();
    int t = lcnt;
    if (t == 0) return;

    float U = 0.f;
    for (int i = tid; i < t; i += 256) U += lse[(size_t)b * P + mem[i]];
    redu[tid] = U; __syncthreads();
    for (int st = 128; st > 0; st >>= 1){
        if (tid < st) redu[tid] += redu[tid + st];
        __syncthreads();
    }
    if (tid == 0) Ufin = redu[0];
    __syncthreads();

    float vh = 0.f;
    if (tid < H128)
        for (int i = 0; i < t; i++)
            vh += bf2f(boxi[((size_t)b * P + mem[i]) * H128 + tid]);
    redu[tid] = (tid < H128) ? vh * vh : 0.f;
    __syncthreads();
    for (int st = 128; st > 0; st >>= 1){
        if (tid < st) redu[tid] += redu[tid + st];
        __syncthreads();
    }
    if (tid == 0){
        float c1 = fmaxf(cnt[b], 1.f);
        atomicAdd(&accf[1], clampf(((float)t * Ufin - redu[0]) / (c1 * c1), -1e5f, 1e5f));
    }
}

// ---------------- K8: finalize ----------------
__global__ void k_fin(const float* __restrict__ accf, const int* __restrict__ flagp,
                      void* __restrict__ out, float invB)
{
    if (threadIdx.x == 0 && blockIdx.x == 0){
        float a = clampf(accf[0] * invB, -1e6f, 1e6f);
        float b = clampf(accf[1] * invB, -1e6f, 1e6f);
        if (*flagp){
            ((float*)out)[0] = a; ((float*)out)[1] = b;
        } else {
            ((u16*)out)[0] = f2bf(a); ((u16*)out)[1] = f2bf(b);
        }
    }
}

extern "C" void kernel_launch(void* const* d_in, const int* in_sizes, int n_in,
                              void* d_out, int out_size, void* d_ws, size_t ws_size,
                              hipStream_t stream)
{
    const void* pred_center = d_in[0];
    const void* pred_size   = d_in[1];
    const void* bbox        = d_in[2];
    const void* gtc         = d_in[3];
    const void* gts         = d_in[4];
    const void* lang        = d_in[5];
    const void* obj         = d_in[6];
    const void* Wt          = d_in[7];
    const void* Wp          = d_in[8];
    const void* Wpi         = d_in[9];
    const int*  lang_raw    = (const int*)d_in[10];

    int B = in_sizes[10];
    int P = in_sizes[0] / (3 * B);
    int L = in_sizes[3] / (3 * B);
    (void)n_in; (void)out_size;

    char* w = (char*)d_ws;
    float* accf  = (float*)w;
    int*   flagp = (int*)(w + 64);
    int*   lni   = (int*)(w + 256);
    char*  chunk_base = w + 512;
    size_t chunk_avail = (ws_size > 512) ? ws_size - 512 : 0;

    size_t per_b = (size_t)P + (size_t)P * 4 + 8 + (size_t)L * 4
                 + (size_t)L * P + (size_t)P * 4
                 + (size_t)P * H128 * 2 * 2 + (size_t)L * H128 * 4;
    size_t slop = 12 * 256;
    int C = B;
    if ((size_t)B * per_b + slop > chunk_avail){
        size_t av = (chunk_avail > slop) ? chunk_avail - slop : 0;
        C = (int)(av / per_b);
        if (C < 1) C = 1;
        if (C > B) C = B;
    }

    k_init<<<1, 64, 0, stream>>>(lang_raw, pred_size, lni, accf, flagp, B);

    for (int b0 = 0; b0 < B; b0 += C){
        int c = (B - b0 < C) ? (B - b0) : C;

        size_t off = 0;
        auto carve = [&](size_t bytes) -> void* {
            void* p = chunk_base + off;
            off = (off + bytes + 255) & ~(size_t)255;
            return p;
        };
        u8*    mask     = (u8*)   carve((size_t)c * P);
        float* cnt      = (float*)carve((size_t)c * 4);
        int*   needcnt  = (int*)  carve((size_t)c * 4);
        float* tcnt     = (float*)carve((size_t)c * L * 4);
        u8*    tgtb     = (u8*)   carve((size_t)c * L * P);
        int*   needlist = (int*)  carve((size_t)c * P * 4);
        float* lse      = (float*)carve((size_t)c * P * 4);
        u16*   boxl     = (u16*)  carve((size_t)c * P * H128 * 2);
        u16*   boxi     = (u16*)  carve((size_t)c * P * H128 * 2);
        float* text     = (float*)carve((size_t)c * L * H128 * 4);

        k_meta<<<c, 256, 0, stream>>>(obj, flagp, mask, cnt, needcnt, b0, P);
        k_tgt <<<c * L, 256, 0, stream>>>(gtc, gts, pred_center, pred_size, flagp,
                                          mask, tgtb, tcnt, b0, P, L);
        k_need<<<c, 256, 0, stream>>>(tgtb, needcnt, needlist, lse, P, L);
        int nb1 = (c * P + 63) / 64;
        int nbt = (c * L + 63) / 64;
        k_proj<<<2 * nb1 + nbt, 256, 0, stream>>>(bbox, lang, Wp, Wpi, Wt, flagp,
                                                  boxl, boxi, text, nb1,
                                                  b0 * P, b0 * L, c * P, c * L);
        k_lang<<<c * L, 256, 0, stream>>>(text, boxl, mask, tgtb, cnt, tcnt, lni, accf, b0, P, L);
        k_lse <<<c * (P / 16), 256, 0, stream>>>(boxi, mask, needcnt, needlist, lse, P, P / 16);
        k_iou <<<c * L, 256, 0, stream>>>(boxi, tgtb, lse, cnt, lni, accf, b0, P, L);
    }

    k_fin<<<1, 64, 0, stream>>>(accf, flagp, d_out, 1.0f / (float)B);
}

// Round 7
// 171.007 us; speedup vs baseline: 1.8214x; 1.3717x over previous
//
#include <hip/hip_runtime.h>
#include <hip/hip_bf16.h>
#include <math.h>

typedef unsigned short u16;
typedef unsigned int   u32;
typedef unsigned char  u8;

typedef __attribute__((ext_vector_type(8))) short short8_t;
typedef __attribute__((ext_vector_type(4))) float f32x4_t;

#define H128 128

__device__ __forceinline__ float bf2f(u16 v){
    u32 u = ((u32)v) << 16;
    return __uint_as_float(u);
}
__device__ __forceinline__ u16 f2bf(float x){
    u32 u = __float_as_uint(x);
    u32 r = (u + 0x7fffu + ((u >> 16) & 1u)) >> 16;
    return (u16)r;
}
__device__ __forceinline__ void unpack8(uint4 v, float* f){
    f[0] = bf2f((u16)(v.x & 0xffff)); f[1] = bf2f((u16)(v.x >> 16));
    f[2] = bf2f((u16)(v.y & 0xffff)); f[3] = bf2f((u16)(v.y >> 16));
    f[4] = bf2f((u16)(v.z & 0xffff)); f[5] = bf2f((u16)(v.z >> 16));
    f[6] = bf2f((u16)(v.w & 0xffff)); f[7] = bf2f((u16)(v.w >> 16));
}
__device__ __forceinline__ float ld1(const void* p, size_t i, int F){
    return F ? ((const float*)p)[i] : bf2f(((const u16*)p)[i]);
}
__device__ __forceinline__ void ld8(const void* p, size_t i, int F, float* f){
    if (F){
        const float* fp = (const float*)p + i;
        float4 a = *(const float4*)fp;
        float4 b = *(const float4*)(fp + 4);
        f[0]=a.x; f[1]=a.y; f[2]=a.z; f[3]=a.w;
        f[4]=b.x; f[5]=b.y; f[6]=b.z; f[7]=b.w;
    } else {
        uint4 v = *(const uint4*)((const u16*)p + i);
        unpack8(v, f);
    }
}
__device__ __forceinline__ float clampf(float x, float lo, float hi){
    return fminf(fmaxf(x, lo), hi);
}

// ---------------- K0: once — dtype detect, accumulators, lang_num decode ----------------
__global__ void k_init(const int* __restrict__ lang_raw, const void* __restrict__ pred_size,
                       int* __restrict__ lni, float* __restrict__ accf,
                       int* __restrict__ flagp, int B)
{
    if (threadIdx.x == 0 && blockIdx.x == 0){
        accf[0] = 0.f; accf[1] = 0.f;
        const u16* ps = (const u16*)pred_size;
        int inr = 0;
        for (int i = 0; i < 128; i++){
            u16 v = ps[i];
            if (v >= 0x3000 && v < 0x4100) inr++;
        }
        *flagp = (inr >= 120) ? 0 : 1;   // 0 = bf16, 1 = f32
        bool is64 = (B >= 8) && lang_raw[1] == 0 && lang_raw[3] == 0 &&
                    lang_raw[5] == 0 && lang_raw[7] == 0;
        for (int i = 0; i < B; i++) lni[i] = is64 ? lang_raw[2 * i] : lang_raw[i];
    }
}

// ---------------- K1: objectness mask + count ----------------
__global__ void __launch_bounds__(256) k_meta(
        const void* __restrict__ obj, const int* __restrict__ Fp,
        u8* __restrict__ mask, float* __restrict__ cnt, int* __restrict__ needcnt,
        int b0, int P)
{
    const int F = *Fp;
    int b = blockIdx.x, tid = threadIdx.x;
    float c = 0.f;
    for (int p = tid; p < P; p += 256){
        size_t base = ((size_t)(b0 + b) * P + p) * 2;
        float s0 = ld1(obj, base, F);
        float s1 = ld1(obj, base + 1, F);
        u8 m = (s1 > s0) ? 1 : 0;
        mask[(size_t)b * P + p] = m;
        c += (float)m;
    }
    __shared__ float red[256];
    red[tid] = c; __syncthreads();
    for (int st = 128; st > 0; st >>= 1){
        if (tid < st) red[tid] += red[tid + st];
        __syncthreads();
    }
    if (tid == 0){ cnt[b] = red[0]; needcnt[b] = 0; }
}

// ---------------- K2: AABB IoU -> tgt (also zeroes lang partials) ----------------
__global__ void __launch_bounds__(256) k_tgt(
        const void* __restrict__ gtc, const void* __restrict__ gts,
        const void* __restrict__ pc_, const void* __restrict__ ps_,
        const int* __restrict__ Fp, const u8* __restrict__ mask,
        u8* __restrict__ tgt, float* __restrict__ tcnt,
        float* __restrict__ sexp, float* __restrict__ sdot,
        int b0, int P, int L)
{
    const int F = *Fp;
    int blk = blockIdx.x, b = blk / L, l = blk % L, tid = threadIdx.x;
    float gmin[3], gmax[3], gs[3];
    for (int i = 0; i < 3; i++){
        size_t gi = ((size_t)(b0 + b) * L + l) * 3 + i;
        float gc = ld1(gtc, gi, F);
        gs[i] = ld1(gts, gi, F) + 0.01f;
        gmin[i] = gc - 0.5f * gs[i];
        gmax[i] = gc + 0.5f * gs[i];
    }
    float volg = gs[0] * gs[1] * gs[2];
    float c = 0.f;
    for (int p = tid; p < P; p += 256){
        size_t base = ((size_t)(b0 + b) * P + p) * 3;
        float inter = 1.f, volp = 1.f;
        for (int i = 0; i < 3; i++){
            float pcv = ld1(pc_, base + i, F);
            float psv = ld1(ps_, base + i, F);
            float mn = fmaxf(gmin[i], pcv - 0.5f * psv);
            float mx = fminf(gmax[i], pcv + 0.5f * psv);
            inter *= fmaxf(mx - mn, 0.f);
            volp  *= psv;
        }
        float iou = inter / (volg + volp - inter + 1e-7f);
        u8 t = (iou > 0.25f && mask[(size_t)b * P + p]) ? 1 : 0;
        tgt[((size_t)b * L + l) * P + p] = t;
        c += (float)t;
    }
    __shared__ float red[256];
    red[tid] = c; __syncthreads();
    for (int st = 128; st > 0; st >>= 1){
        if (tid < st) red[tid] += red[tid + st];
        __syncthreads();
    }
    if (tid == 0){
        tcnt[b * L + l] = red[0];
        sexp[b * L + l] = 0.f;
        sdot[b * L + l] = 0.f;
    }
}

// ---------------- K3: compact rows needing LSE_q; zero lse (sum-exp accumulator) ----------------
__global__ void __launch_bounds__(256) k_need(
        const u8* __restrict__ tgt, int* __restrict__ needcnt,
        int* __restrict__ needlist, float* __restrict__ lse, int P, int L)
{
    int b = blockIdx.x;
    for (int p = threadIdx.x; p < P; p += 256){
        lse[(size_t)b * P + p] = 0.f;
        bool any = false;
        for (int l = 0; l < L; l++) any |= (tgt[((size_t)b * L + l) * P + p] != 0);
        if (any){
            int pos = atomicAdd(&needcnt[b], 1);
            needlist[(size_t)b * P + pos] = p;
        }
    }
}

// ---------------- K4: projections + normalize — bf16 MFMA (all outputs bf16) ----------------
__global__ void __launch_bounds__(256) k_proj(
        const void* __restrict__ bbox, const void* __restrict__ lang,
        const void* __restrict__ Wp, const void* __restrict__ Wpi, const void* __restrict__ Wt,
        const int* __restrict__ Fp,
        u16* __restrict__ boxl, u16* __restrict__ boxi, u16* __restrict__ text,
        int nb1, int rowoff_bp, int rowoff_t, int nrows_bp, int nrows_t)
{
    const int F = *Fp;
    int blk = blockIdx.x, tid = threadIdx.x;
    const void *X, *W; u16* outb; int row0, nrows, rowoff;
    if (blk < nb1)          { X = bbox; W = Wp;  outb = boxl; row0 = blk * 64;             nrows = nrows_bp; rowoff = rowoff_bp; }
    else if (blk < 2 * nb1) { X = bbox; W = Wpi; outb = boxi; row0 = (blk - nb1) * 64;     nrows = nrows_bp; rowoff = rowoff_bp; }
    else                    { X = lang; W = Wt;  outb = text; row0 = (blk - 2 * nb1) * 64; nrows = nrows_t;  rowoff = rowoff_t; }

    __shared__ __align__(16) u16 Ws[128 * H128];
    __shared__ __align__(16) u16 Xs[64 * H128];

    for (int i = 0; i < 8; i++){
        int cid = tid + i * 256;
        int r = cid >> 4, cc = cid & 15;
        float f[8];
        ld8(W, (size_t)r * H128 + cc * 8, F, f);
        u16* dst = &Ws[r * H128 + ((cc ^ (r & 15)) * 8)];
        #pragma unroll
        for (int j = 0; j < 8; j++) dst[j] = f2bf(f[j]);
    }
    for (int i = 0; i < 4; i++){
        int cid = tid + i * 256;
        int r = cid >> 4, cc = cid & 15;
        int row = row0 + r;
        float f[8];
        if (row < nrows){
            ld8(X, (size_t)(rowoff + row) * H128 + cc * 8, F, f);
        } else {
            #pragma unroll
            for (int j = 0; j < 8; j++) f[j] = 0.f;
        }
        u16* dst = &Xs[r * H128 + ((cc ^ (r & 15)) * 8)];
        #pragma unroll
        for (int j = 0; j < 8; j++) dst[j] = f2bf(f[j]);
    }
    __syncthreads();

    int w = tid >> 6, lane = tid & 63;
    int quad = lane >> 4, mrow = lane & 15;

    short8_t af[4];
    int arow = w * 16 + mrow;
    #pragma unroll
    for (int kt = 0; kt < 4; kt++){
        int chunk = kt * 4 + quad;
        af[kt] = *(const short8_t*)&Xs[arow * H128 + ((chunk ^ mrow) * 8)];
    }

    f32x4_t acc[8];
    #pragma unroll
    for (int nt = 0; nt < 8; nt++) acc[nt] = (f32x4_t){0.f, 0.f, 0.f, 0.f};

    #pragma unroll
    for (int nt = 0; nt < 8; nt++){
        int n = nt * 16 + mrow;
        #pragma unroll
        for (int kt = 0; kt < 4; kt++){
            int chunk = kt * 4 + quad;
            short8_t bf = *(const short8_t*)&Ws[n * H128 + ((chunk ^ mrow) * 8)];
            acc[nt] = __builtin_amdgcn_mfma_f32_16x16x32_bf16(af[kt], bf, acc[nt], 0, 0, 0);
        }
    }

    float ss[4] = {0.f, 0.f, 0.f, 0.f};
    #pragma unroll
    for (int nt = 0; nt < 8; nt++)
        #pragma unroll
        for (int reg = 0; reg < 4; reg++) ss[reg] += acc[nt][reg] * acc[nt][reg];
    #pragma unroll
    for (int off = 1; off <= 8; off <<= 1)
        #pragma unroll
        for (int reg = 0; reg < 4; reg++) ss[reg] += __shfl_xor(ss[reg], off);
    float rn[4];
    #pragma unroll
    for (int reg = 0; reg < 4; reg++) rn[reg] = 1.0f / fmaxf(sqrtf(ss[reg]), 1e-12f);

    #pragma unroll
    for (int reg = 0; reg < 4; reg++){
        int row = row0 + w * 16 + quad * 4 + reg;
        if (row < nrows){
            #pragma unroll
            for (int nt = 0; nt < 8; nt++){
                int col = nt * 16 + mrow;
                outb[(size_t)row * H128 + col] = f2bf(acc[nt][reg] * rn[reg]);
            }
        }
    }
}

// ---------------- K5: lang NCE — MFMA GEMM over col-tiles, atomic partials ----------------
// grid: c * (P/128). Block: text[b] (L=32 rows) x 128 boxl cols.
__global__ void __launch_bounds__(256) k_lang(
        const u16* __restrict__ text, const u16* __restrict__ boxl,
        const u8* __restrict__ mask, const u8* __restrict__ tgt,
        float* __restrict__ sexp, float* __restrict__ sdot, int P, int L)
{
    int nct = P >> 7;
    int b = blockIdx.x / nct, ct = blockIdx.x % nct;
    int p0 = ct * 128;
    int tid = threadIdx.x;

    __shared__ __align__(16) u16 As[32 * H128];
    __shared__ __align__(16) u16 Bs[128 * H128];
    __shared__ u8 Ts[32 * 128];
    __shared__ u8 mk[128];

    for (int i = 0; i < 2; i++){
        int cid = tid + i * 256;
        int r = cid >> 4, cc = cid & 15;
        uint4 v = *(const uint4*)&text[((size_t)b * L + r) * H128 + cc * 8];
        *(uint4*)&As[r * H128 + ((cc ^ (r & 15)) * 8)] = v;
    }
    for (int i = 0; i < 8; i++){
        int cid = tid + i * 256;
        int r = cid >> 4, cc = cid & 15;
        uint4 v = *(const uint4*)&boxl[((size_t)b * P + p0 + r) * H128 + cc * 8];
        *(uint4*)&Bs[r * H128 + ((cc ^ (r & 15)) * 8)] = v;
    }
    {   // tgt tile: 32 l x 128 p = 4096 B
        int l = tid >> 3, seg = tid & 7;
        uint4 v = *(const uint4*)&tgt[((size_t)b * L + l) * P + p0 + seg * 16];
        *(uint4*)&Ts[l * 128 + seg * 16] = v;
    }
    if (tid < 128) mk[tid] = mask[(size_t)b * P + p0 + tid];
    __syncthreads();

    int w = tid >> 6, lane = tid & 63;
    int quad = lane >> 4, mrow = lane & 15;
    int mt = w & 1;        // which 16 l-rows
    int ch = w >> 1;       // which 64-col half

    short8_t af[4];
    #pragma unroll
    for (int kt = 0; kt < 4; kt++){
        int chunk = kt * 4 + quad;
        af[kt] = *(const short8_t*)&As[(mt * 16 + mrow) * H128 + ((chunk ^ mrow) * 8)];
    }

    float se[4] = {0.f, 0.f, 0.f, 0.f};
    float sd[4] = {0.f, 0.f, 0.f, 0.f};
    #pragma unroll
    for (int nt = 0; nt < 4; nt++){
        int cl = ch * 64 + nt * 16 + mrow;    // col local, cl&15 == mrow
        f32x4_t acc = (f32x4_t){0.f, 0.f, 0.f, 0.f};
        #pragma unroll
        for (int kt = 0; kt < 4; kt++){
            int chunk = kt * 4 + quad;
            short8_t bf = *(const short8_t*)&Bs[cl * H128 + ((chunk ^ mrow) * 8)];
            acc = __builtin_amdgcn_mfma_f32_16x16x32_bf16(af[kt], bf, acc, 0, 0, 0);
        }
        float m = mk[cl] ? 1.f : 0.f;
        #pragma unroll
        for (int reg = 0; reg < 4; reg++){
            int l = mt * 16 + quad * 4 + reg;
            float d = acc[reg];
            se[reg] += m * __expf(d);
            if (m != 0.f && Ts[l * 128 + cl]) sd[reg] += d;
        }
    }
    #pragma unroll
    for (int off = 1; off <= 8; off <<= 1)
        #pragma unroll
        for (int reg = 0; reg < 4; reg++){
            se[reg] += __shfl_xor(se[reg], off);
            sd[reg] += __shfl_xor(sd[reg], off);
        }
    if (mrow == 0){
        #pragma unroll
        for (int reg = 0; reg < 4; reg++){
            int l = mt * 16 + quad * 4 + reg;
            atomicAdd(&sexp[b * L + l], se[reg]);
            atomicAdd(&sdot[b * L + l], sd[reg]);
        }
    }
}

// ---------------- K6: sum-exp over q for needed rows — MFMA, col-tiled, atomic ----------------
// grid: c * (P/128). Block stages 128 q-rows once; streams needlist row-tiles.
__global__ void __launch_bounds__(256) k_lse(
        const u16* __restrict__ boxi, const u8* __restrict__ mask,
        const int* __restrict__ needcnt, const int* __restrict__ needlist,
        float* __restrict__ lse, int P)
{
    int nct = P >> 7;
    int b = blockIdx.x / nct, ct = blockIdx.x % nct;
    int q0 = ct * 128;
    int ncnt = needcnt[b];
    if (ncnt <= 0) return;
    int tid = threadIdx.x;

    __shared__ __align__(16) u16 Bs[128 * H128];
    __shared__ u8 mk[128];
    for (int i = 0; i < 8; i++){
        int cid = tid + i * 256;
        int r = cid >> 4, cc = cid & 15;
        uint4 v = *(const uint4*)&boxi[((size_t)b * P + q0 + r) * H128 + cc * 8];
        *(uint4*)&Bs[r * H128 + ((cc ^ (r & 15)) * 8)] = v;
    }
    if (tid < 128) mk[tid] = mask[(size_t)b * P + q0 + tid];
    __syncthreads();

    int w = tid >> 6, lane = tid & 63;
    int quad = lane >> 4, mrow = lane & 15;
    int nrt = (ncnt + 15) >> 4;

    for (int rt = w; rt < nrt; rt += 4){
        int i = rt * 16 + mrow;
        int prow = needlist[(size_t)b * P + ((i < ncnt) ? i : (ncnt - 1))];
        const u16* ab = &boxi[((size_t)b * P + prow) * H128];
        short8_t af[4];
        #pragma unroll
        for (int kt = 0; kt < 4; kt++)
            af[kt] = *(const short8_t*)&ab[(kt * 4 + quad) * 8];

        float se[4] = {0.f, 0.f, 0.f, 0.f};
        #pragma unroll
        for (int nt = 0; nt < 8; nt++){
            int cl = nt * 16 + mrow;
            f32x4_t acc = (f32x4_t){0.f, 0.f, 0.f, 0.f};
            #pragma unroll
            for (int kt = 0; kt < 4; kt++){
                int chunk = kt * 4 + quad;
                short8_t bf = *(const short8_t*)&Bs[cl * H128 + ((chunk ^ mrow) * 8)];
                acc = __builtin_amdgcn_mfma_f32_16x16x32_bf16(af[kt], bf, acc, 0, 0, 0);
            }
            float m = mk[cl] ? 1.f : 0.f;
            #pragma unroll
            for (int reg = 0; reg < 4; reg++) se[reg] += m * __expf(acc[reg]);
        }
        #pragma unroll
        for (int off = 1; off <= 8; off <<= 1)
            #pragma unroll
            for (int reg = 0; reg < 4; reg++) se[reg] += __shfl_xor(se[reg], off);
        if (mrow == 0){
            #pragma unroll
            for (int reg = 0; reg < 4; reg++){
                int i2 = rt * 16 + quad * 4 + reg;
                if (i2 < ncnt)
                    atomicAdd(&lse[(size_t)b * P + needlist[(size_t)b * P + i2]], se[reg]);
            }
        }
    }
}

// ---------------- K7: per (b,l) — lang finalize + iou NCE ----------------
__global__ void __launch_bounds__(256) k_iou(
        const u16* __restrict__ boxi, const u8* __restrict__ tgt,
        const float* __restrict__ lse, const float* __restrict__ cnt,
        const float* __restrict__ tcnt, const float* __restrict__ sexp,
        const float* __restrict__ sdot, const int* __restrict__ lni,
        float* __restrict__ accf, int b0, int P, int L)
{
    int blk = blockIdx.x, b = blk / L, l = blk % L, tid = threadIdx.x;
    if (l >= lni[b0 + b]) return;
    float tf = tcnt[b * L + l];
    if (tf <= 0.f) return;
    float c1 = fmaxf(cnt[b], 1.f);

    if (tid == 0){
        // lang loss: 0.5*(t*LSE - sum_{p in T} dot)/cnt1
        float LSE = logf(fmaxf(sexp[b * L + l], 1e-30f));
        atomicAdd(&accf[0], clampf(0.5f * (tf * LSE - sdot[b * L + l]) / c1, -1e5f, 1e5f));
    }

    __shared__ int mem[1024];
    __shared__ int lcnt;
    __shared__ float redu[256];
    __shared__ float Ufin;
    if (tid == 0) lcnt = 0;
    __syncthreads();
    for (int p = tid; p < P; p += 256)
        if (tgt[((size_t)b * L + l) * P + p])
            mem[atomicAdd(&lcnt, 1)] = p;
    __syncthreads();
    int t = lcnt;

    float U = 0.f;
    for (int i = tid; i < t; i += 256)
        U += logf(fmaxf(lse[(size_t)b * P + mem[i]], 1e-30f));
    redu[tid] = U; __syncthreads();
    for (int st = 128; st > 0; st >>= 1){
        if (tid < st) redu[tid] += redu[tid + st];
        __syncthreads();
    }
    if (tid == 0) Ufin = redu[0];
    __syncthreads();

    float vh = 0.f;
    if (tid < H128)
        for (int i = 0; i < t; i++)
            vh += bf2f(boxi[((size_t)b * P + mem[i]) * H128 + tid]);
    redu[tid] = (tid < H128) ? vh * vh : 0.f;
    __syncthreads();
    for (int st = 128; st > 0; st >>= 1){
        if (tid < st) redu[tid] += redu[tid + st];
        __syncthreads();
    }
    if (tid == 0)
        atomicAdd(&accf[1], clampf(((float)t * Ufin - redu[0]) / (c1 * c1), -1e5f, 1e5f));
}

// ---------------- K8: finalize ----------------
__global__ void k_fin(const float* __restrict__ accf, const int* __restrict__ flagp,
                      void* __restrict__ out, float invB)
{
    if (threadIdx.x == 0 && blockIdx.x == 0){
        float a = clampf(accf[0] * invB, -1e6f, 1e6f);
        float b = clampf(accf[1] * invB, -1e6f, 1e6f);
        if (*flagp){
            ((float*)out)[0] = a; ((float*)out)[1] = b;
        } else {
            ((u16*)out)[0] = f2bf(a); ((u16*)out)[1] = f2bf(b);
        }
    }
}

extern "C" void kernel_launch(void* const* d_in, const int* in_sizes, int n_in,
                              void* d_out, int out_size, void* d_ws, size_t ws_size,
                              hipStream_t stream)
{
    const void* pred_center = d_in[0];
    const void* pred_size   = d_in[1];
    const void* bbox        = d_in[2];
    const void* gtc         = d_in[3];
    const void* gts         = d_in[4];
    const void* lang        = d_in[5];
    const void* obj         = d_in[6];
    const void* Wt          = d_in[7];
    const void* Wp          = d_in[8];
    const void* Wpi         = d_in[9];
    const int*  lang_raw    = (const int*)d_in[10];

    int B = in_sizes[10];
    int P = in_sizes[0] / (3 * B);
    int L = in_sizes[3] / (3 * B);
    (void)n_in; (void)out_size;

    char* w = (char*)d_ws;
    float* accf  = (float*)w;
    int*   flagp = (int*)(w + 64);
    int*   lni   = (int*)(w + 256);
    char*  chunk_base = w + 512;
    size_t chunk_avail = (ws_size > 512) ? ws_size - 512 : 0;

    size_t per_b = (size_t)P + (size_t)P * 4 + 8 + (size_t)L * 4 * 3
                 + (size_t)L * P + (size_t)P * 4
                 + (size_t)P * H128 * 2 * 2 + (size_t)L * H128 * 2;
    size_t slop = 14 * 256;
    int C = B;
    if ((size_t)B * per_b + slop > chunk_avail){
        size_t av = (chunk_avail > slop) ? chunk_avail - slop : 0;
        C = (int)(av / per_b);
        if (C < 1) C = 1;
        if (C > B) C = B;
    }

    k_init<<<1, 64, 0, stream>>>(lang_raw, pred_size, lni, accf, flagp, B);

    for (int b0 = 0; b0 < B; b0 += C){
        int c = (B - b0 < C) ? (B - b0) : C;

        size_t off = 0;
        auto carve = [&](size_t bytes) -> void* {
            void* p = chunk_base + off;
            off = (off + bytes + 255) & ~(size_t)255;
            return p;
        };
        u8*    mask     = (u8*)   carve((size_t)c * P);
        float* cnt      = (float*)carve((size_t)c * 4);
        int*   needcnt  = (int*)  carve((size_t)c * 4);
        float* tcnt     = (float*)carve((size_t)c * L * 4);
        float* sexp     = (float*)carve((size_t)c * L * 4);
        float* sdot     = (float*)carve((size_t)c * L * 4);
        u8*    tgtb     = (u8*)   carve((size_t)c * L * P);
        int*   needlist = (int*)  carve((size_t)c * P * 4);
        float* lse      = (float*)carve((size_t)c * P * 4);
        u16*   boxl     = (u16*)  carve((size_t)c * P * H128 * 2);
        u16*   boxi     = (u16*)  carve((size_t)c * P * H128 * 2);
        u16*   text     = (u16*)  carve((size_t)c * L * H128 * 2);

        k_meta<<<c, 256, 0, stream>>>(obj, flagp, mask, cnt, needcnt, b0, P);
        k_tgt <<<c * L, 256, 0, stream>>>(gtc, gts, pred_center, pred_size, flagp,
                                          mask, tgtb, tcnt, sexp, sdot, b0, P, L);
        k_need<<<c, 256, 0, stream>>>(tgtb, needcnt, needlist, lse, P, L);
        int nb1 = (c * P + 63) / 64;
        int nbt = (c * L + 63) / 64;
        k_proj<<<2 * nb1 + nbt, 256, 0, stream>>>(bbox, lang, Wp, Wpi, Wt, flagp,
                                                  boxl, boxi, text, nb1,
                                                  b0 * P, b0 * L, c * P, c * L);
        k_lang<<<c * (P / 128), 256, 0, stream>>>(text, boxl, mask, tgtb, sexp, sdot, P, L);
        k_lse <<<c * (P / 128), 256, 0, stream>>>(boxi, mask, needcnt, needlist, lse, P);
        k_iou <<<c * L, 256, 0, stream>>>(boxi, tgtb, lse, cnt, tcnt, sexp, sdot,
                                          lni, accf, b0, P, L);
    }

    k_fin<<<1, 64, 0, stream>>>(accf, flagp, d_out, 1.0f / (float)B);
}

// Round 8
// 168.792 us; speedup vs baseline: 1.8453x; 1.0131x over previous
//
#include <hip/hip_runtime.h>
#include <hip/hip_bf16.h>
#include <math.h>

typedef unsigned short u16;
typedef unsigned int   u32;
typedef unsigned char  u8;
typedef unsigned long long u64;

typedef __attribute__((ext_vector_type(8))) short short8_t;
typedef __attribute__((ext_vector_type(4))) float f32x4_t;

#define H128 128

__device__ __forceinline__ float bf2f(u16 v){
    u32 u = ((u32)v) << 16;
    return __uint_as_float(u);
}
__device__ __forceinline__ u16 f2bf(float x){
    u32 u = __float_as_uint(x);
    u32 r = (u + 0x7fffu + ((u >> 16) & 1u)) >> 16;
    return (u16)r;
}
__device__ __forceinline__ void unpack8(uint4 v, float* f){
    f[0] = bf2f((u16)(v.x & 0xffff)); f[1] = bf2f((u16)(v.x >> 16));
    f[2] = bf2f((u16)(v.y & 0xffff)); f[3] = bf2f((u16)(v.y >> 16));
    f[4] = bf2f((u16)(v.z & 0xffff)); f[5] = bf2f((u16)(v.z >> 16));
    f[6] = bf2f((u16)(v.w & 0xffff)); f[7] = bf2f((u16)(v.w >> 16));
}
__device__ __forceinline__ float ld1(const void* p, size_t i, int F){
    return F ? ((const float*)p)[i] : bf2f(((const u16*)p)[i]);
}
__device__ __forceinline__ void ld8(const void* p, size_t i, int F, float* f){
    if (F){
        const float* fp = (const float*)p + i;
        float4 a = *(const float4*)fp;
        float4 b = *(const float4*)(fp + 4);
        f[0]=a.x; f[1]=a.y; f[2]=a.z; f[3]=a.w;
        f[4]=b.x; f[5]=b.y; f[6]=b.z; f[7]=b.w;
    } else {
        uint4 v = *(const uint4*)((const u16*)p + i);
        unpack8(v, f);
    }
}
__device__ __forceinline__ float clampf(float x, float lo, float hi){
    return fminf(fmaxf(x, lo), hi);
}

// ---------------- K0: dtype detect, accumulators, lang_num decode (parallel) ----------------
__global__ void __launch_bounds__(64) k_init(
        const int* __restrict__ lang_raw, const void* __restrict__ pred_size,
        int* __restrict__ lni, float* __restrict__ accf, int* __restrict__ flagp, int B)
{
    int tid = threadIdx.x;
    __shared__ int cnt_in_range;
    __shared__ int is64_s;
    if (tid == 0){ cnt_in_range = 0; accf[0] = 0.f; accf[1] = 0.f; }
    __syncthreads();
    {   // dtype probe: 128 u16s of pred_size, 2 per thread
        const u16* ps = (const u16*)pred_size;
        int c = 0;
        u16 v0 = ps[tid], v1 = ps[tid + 64];
        if (v0 >= 0x3000 && v0 < 0x4100) c++;
        if (v1 >= 0x3000 && v1 < 0x4100) c++;
        atomicAdd(&cnt_in_range, c);   // LDS atomic, 64 lanes, cheap
    }
    if (tid == 0){
        is64_s = ((B >= 8) && lang_raw[1] == 0 && lang_raw[3] == 0 &&
                  lang_raw[5] == 0 && lang_raw[7] == 0) ? 1 : 0;
    }
    __syncthreads();
    if (tid == 0) *flagp = (cnt_in_range >= 120) ? 0 : 1;   // 0 = bf16, 1 = f32
    if (tid < B) lni[tid] = is64_s ? lang_raw[2 * tid] : lang_raw[tid];
}

// ---------------- K1: objectness mask + count ----------------
__global__ void __launch_bounds__(256) k_meta(
        const void* __restrict__ obj, const int* __restrict__ Fp,
        u8* __restrict__ mask, float* __restrict__ cnt, int b0, int P)
{
    const int F = *Fp;
    int b = blockIdx.x, tid = threadIdx.x;
    float c = 0.f;
    for (int p = tid; p < P; p += 256){
        size_t base = ((size_t)(b0 + b) * P + p) * 2;
        float s0 = ld1(obj, base, F);
        float s1 = ld1(obj, base + 1, F);
        u8 m = (s1 > s0) ? 1 : 0;
        mask[(size_t)b * P + p] = m;
        c += (float)m;
    }
    __shared__ float red[256];
    red[tid] = c; __syncthreads();
    for (int st = 128; st > 0; st >>= 1){
        if (tid < st) red[tid] += red[tid + st];
        __syncthreads();
    }
    if (tid == 0) cnt[b] = red[0];
}

// ---------------- K2: AABB IoU -> tgt (also zeroes lang partials) ----------------
__global__ void __launch_bounds__(256) k_tgt(
        const void* __restrict__ gtc, const void* __restrict__ gts,
        const void* __restrict__ pc_, const void* __restrict__ ps_,
        const int* __restrict__ Fp, const u8* __restrict__ mask,
        u8* __restrict__ tgt, float* __restrict__ tcnt,
        float* __restrict__ sexp, float* __restrict__ sdot,
        int b0, int P, int L)
{
    const int F = *Fp;
    int blk = blockIdx.x, b = blk / L, l = blk % L, tid = threadIdx.x;
    float gmin[3], gmax[3], gs[3];
    for (int i = 0; i < 3; i++){
        size_t gi = ((size_t)(b0 + b) * L + l) * 3 + i;
        float gc = ld1(gtc, gi, F);
        gs[i] = ld1(gts, gi, F) + 0.01f;
        gmin[i] = gc - 0.5f * gs[i];
        gmax[i] = gc + 0.5f * gs[i];
    }
    float volg = gs[0] * gs[1] * gs[2];
    float c = 0.f;
    for (int p = tid; p < P; p += 256){
        size_t base = ((size_t)(b0 + b) * P + p) * 3;
        float inter = 1.f, volp = 1.f;
        for (int i = 0; i < 3; i++){
            float pcv = ld1(pc_, base + i, F);
            float psv = ld1(ps_, base + i, F);
            float mn = fmaxf(gmin[i], pcv - 0.5f * psv);
            float mx = fminf(gmax[i], pcv + 0.5f * psv);
            inter *= fmaxf(mx - mn, 0.f);
            volp  *= psv;
        }
        float iou = inter / (volg + volp - inter + 1e-7f);
        u8 t = (iou > 0.25f && mask[(size_t)b * P + p]) ? 1 : 0;
        tgt[((size_t)b * L + l) * P + p] = t;
        c += (float)t;
    }
    __shared__ float red[256];
    red[tid] = c; __syncthreads();
    for (int st = 128; st > 0; st >>= 1){
        if (tid < st) red[tid] += red[tid + st];
        __syncthreads();
    }
    if (tid == 0){
        tcnt[b * L + l] = red[0];
        sexp[b * L + l] = 0.f;
        sdot[b * L + l] = 0.f;
    }
}

// ---------------- K3: compact rows needing sum-exp — ballot scan, NO atomics ----------------
__global__ void __launch_bounds__(256) k_need(
        const u8* __restrict__ tgt, int* __restrict__ needcnt,
        int* __restrict__ needlist, float* __restrict__ lse, int P, int L)
{
    int b = blockIdx.x, tid = threadIdx.x;
    int wid = tid >> 6, lane = tid & 63;
    __shared__ int wbase[4];
    __shared__ int total;
    if (tid == 0) total = 0;
    __syncthreads();
    for (int k = 0; k < P / 256; k++){
        int p = tid + k * 256;
        lse[(size_t)b * P + p] = 0.f;
        bool any = false;
        for (int l = 0; l < L; l++) any |= (tgt[((size_t)b * L + l) * P + p] != 0);
        u64 bal = __ballot(any);
        if (lane == 0) wbase[wid] = __popcll(bal);
        __syncthreads();
        if (tid == 0){
            int s = total;
            for (int w = 0; w < 4; w++){ int c = wbase[w]; wbase[w] = s; s += c; }
            total = s;
        }
        __syncthreads();
        if (any){
            int rank = __popcll(bal & ((1ULL << lane) - 1ULL));
            needlist[(size_t)b * P + wbase[wid] + rank] = p;
        }
        __syncthreads();
    }
    if (tid == 0) needcnt[b] = total;
}

// ---------------- K4: projections + normalize — bf16 MFMA ----------------
__global__ void __launch_bounds__(256) k_proj(
        const void* __restrict__ bbox, const void* __restrict__ lang,
        const void* __restrict__ Wp, const void* __restrict__ Wpi, const void* __restrict__ Wt,
        const int* __restrict__ Fp,
        u16* __restrict__ boxl, u16* __restrict__ boxi, u16* __restrict__ text,
        int nb1, int rowoff_bp, int rowoff_t, int nrows_bp, int nrows_t)
{
    const int F = *Fp;
    int blk = blockIdx.x, tid = threadIdx.x;
    const void *X, *W; u16* outb; int row0, nrows, rowoff;
    if (blk < nb1)          { X = bbox; W = Wp;  outb = boxl; row0 = blk * 64;             nrows = nrows_bp; rowoff = rowoff_bp; }
    else if (blk < 2 * nb1) { X = bbox; W = Wpi; outb = boxi; row0 = (blk - nb1) * 64;     nrows = nrows_bp; rowoff = rowoff_bp; }
    else                    { X = lang; W = Wt;  outb = text; row0 = (blk - 2 * nb1) * 64; nrows = nrows_t;  rowoff = rowoff_t; }

    __shared__ __align__(16) u16 Ws[128 * H128];
    __shared__ __align__(16) u16 Xs[64 * H128];

    for (int i = 0; i < 8; i++){
        int cid = tid + i * 256;
        int r = cid >> 4, cc = cid & 15;
        float f[8];
        ld8(W, (size_t)r * H128 + cc * 8, F, f);
        u16* dst = &Ws[r * H128 + ((cc ^ (r & 15)) * 8)];
        #pragma unroll
        for (int j = 0; j < 8; j++) dst[j] = f2bf(f[j]);
    }
    for (int i = 0; i < 4; i++){
        int cid = tid + i * 256;
        int r = cid >> 4, cc = cid & 15;
        int row = row0 + r;
        float f[8];
        if (row < nrows){
            ld8(X, (size_t)(rowoff + row) * H128 + cc * 8, F, f);
        } else {
            #pragma unroll
            for (int j = 0; j < 8; j++) f[j] = 0.f;
        }
        u16* dst = &Xs[r * H128 + ((cc ^ (r & 15)) * 8)];
        #pragma unroll
        for (int j = 0; j < 8; j++) dst[j] = f2bf(f[j]);
    }
    __syncthreads();

    int w = tid >> 6, lane = tid & 63;
    int quad = lane >> 4, mrow = lane & 15;

    short8_t af[4];
    int arow = w * 16 + mrow;
    #pragma unroll
    for (int kt = 0; kt < 4; kt++){
        int chunk = kt * 4 + quad;
        af[kt] = *(const short8_t*)&Xs[arow * H128 + ((chunk ^ mrow) * 8)];
    }

    f32x4_t acc[8];
    #pragma unroll
    for (int nt = 0; nt < 8; nt++) acc[nt] = (f32x4_t){0.f, 0.f, 0.f, 0.f};

    #pragma unroll
    for (int nt = 0; nt < 8; nt++){
        int n = nt * 16 + mrow;
        #pragma unroll
        for (int kt = 0; kt < 4; kt++){
            int chunk = kt * 4 + quad;
            short8_t bf = *(const short8_t*)&Ws[n * H128 + ((chunk ^ mrow) * 8)];
            acc[nt] = __builtin_amdgcn_mfma_f32_16x16x32_bf16(af[kt], bf, acc[nt], 0, 0, 0);
        }
    }

    float ss[4] = {0.f, 0.f, 0.f, 0.f};
    #pragma unroll
    for (int nt = 0; nt < 8; nt++)
        #pragma unroll
        for (int reg = 0; reg < 4; reg++) ss[reg] += acc[nt][reg] * acc[nt][reg];
    #pragma unroll
    for (int off = 1; off <= 8; off <<= 1)
        #pragma unroll
        for (int reg = 0; reg < 4; reg++) ss[reg] += __shfl_xor(ss[reg], off);
    float rn[4];
    #pragma unroll
    for (int reg = 0; reg < 4; reg++) rn[reg] = 1.0f / fmaxf(sqrtf(ss[reg]), 1e-12f);

    #pragma unroll
    for (int reg = 0; reg < 4; reg++){
        int row = row0 + w * 16 + quad * 4 + reg;
        if (row < nrows){
            #pragma unroll
            for (int nt = 0; nt < 8; nt++){
                int col = nt * 16 + mrow;
                outb[(size_t)row * H128 + col] = f2bf(acc[nt][reg] * rn[reg]);
            }
        }
    }
}

// ---------------- K5: lang NCE — MFMA GEMM over col-tiles, atomic partials ----------------
__global__ void __launch_bounds__(256) k_lang(
        const u16* __restrict__ text, const u16* __restrict__ boxl,
        const u8* __restrict__ mask, const u8* __restrict__ tgt,
        float* __restrict__ sexp, float* __restrict__ sdot, int P, int L)
{
    int nct = P >> 7;
    int b = blockIdx.x / nct, ct = blockIdx.x % nct;
    int p0 = ct * 128;
    int tid = threadIdx.x;

    __shared__ __align__(16) u16 As[32 * H128];
    __shared__ __align__(16) u16 Bs[128 * H128];
    __shared__ u8 Ts[32 * 128];
    __shared__ u8 mk[128];

    for (int i = 0; i < 2; i++){
        int cid = tid + i * 256;
        int r = cid >> 4, cc = cid & 15;
        uint4 v = *(const uint4*)&text[((size_t)b * L + r) * H128 + cc * 8];
        *(uint4*)&As[r * H128 + ((cc ^ (r & 15)) * 8)] = v;
    }
    for (int i = 0; i < 8; i++){
        int cid = tid + i * 256;
        int r = cid >> 4, cc = cid & 15;
        uint4 v = *(const uint4*)&boxl[((size_t)b * P + p0 + r) * H128 + cc * 8];
        *(uint4*)&Bs[r * H128 + ((cc ^ (r & 15)) * 8)] = v;
    }
    {
        int l = tid >> 3, seg = tid & 7;
        uint4 v = *(const uint4*)&tgt[((size_t)b * L + l) * P + p0 + seg * 16];
        *(uint4*)&Ts[l * 128 + seg * 16] = v;
    }
    if (tid < 128) mk[tid] = mask[(size_t)b * P + p0 + tid];
    __syncthreads();

    int w = tid >> 6, lane = tid & 63;
    int quad = lane >> 4, mrow = lane & 15;
    int mt = w & 1;
    int ch = w >> 1;

    short8_t af[4];
    #pragma unroll
    for (int kt = 0; kt < 4; kt++){
        int chunk = kt * 4 + quad;
        af[kt] = *(const short8_t*)&As[(mt * 16 + mrow) * H128 + ((chunk ^ mrow) * 8)];
    }

    float se[4] = {0.f, 0.f, 0.f, 0.f};
    float sd[4] = {0.f, 0.f, 0.f, 0.f};
    #pragma unroll
    for (int nt = 0; nt < 4; nt++){
        int cl = ch * 64 + nt * 16 + mrow;
        f32x4_t acc = (f32x4_t){0.f, 0.f, 0.f, 0.f};
        #pragma unroll
        for (int kt = 0; kt < 4; kt++){
            int chunk = kt * 4 + quad;
            short8_t bf = *(const short8_t*)&Bs[cl * H128 + ((chunk ^ mrow) * 8)];
            acc = __builtin_amdgcn_mfma_f32_16x16x32_bf16(af[kt], bf, acc, 0, 0, 0);
        }
        float m = mk[cl] ? 1.f : 0.f;
        #pragma unroll
        for (int reg = 0; reg < 4; reg++){
            int l = mt * 16 + quad * 4 + reg;
            float d = acc[reg];
            se[reg] += m * __expf(d);
            if (m != 0.f && Ts[l * 128 + cl]) sd[reg] += d;
        }
    }
    #pragma unroll
    for (int off = 1; off <= 8; off <<= 1)
        #pragma unroll
        for (int reg = 0; reg < 4; reg++){
            se[reg] += __shfl_xor(se[reg], off);
            sd[reg] += __shfl_xor(sd[reg], off);
        }
    if (mrow == 0){
        #pragma unroll
        for (int reg = 0; reg < 4; reg++){
            int l = mt * 16 + quad * 4 + reg;
            atomicAdd(&sexp[b * L + l], se[reg]);
            atomicAdd(&sdot[b * L + l], sd[reg]);
        }
    }
}

// ---------------- K6: sum-exp over q for needed rows — MFMA, col-tiled, atomic ----------------
__global__ void __launch_bounds__(256) k_lse(
        const u16* __restrict__ boxi, const u8* __restrict__ mask,
        const int* __restrict__ needcnt, const int* __restrict__ needlist,
        float* __restrict__ lse, int P)
{
    int nct = P >> 7;
    int b = blockIdx.x / nct, ct = blockIdx.x % nct;
    int q0 = ct * 128;
    int ncnt = needcnt[b];
    if (ncnt <= 0) return;
    int tid = threadIdx.x;

    __shared__ __align__(16) u16 Bs[128 * H128];
    __shared__ u8 mk[128];
    for (int i = 0; i < 8; i++){
        int cid = tid + i * 256;
        int r = cid >> 4, cc = cid & 15;
        uint4 v = *(const uint4*)&boxi[((size_t)b * P + q0 + r) * H128 + cc * 8];
        *(uint4*)&Bs[r * H128 + ((cc ^ (r & 15)) * 8)] = v;
    }
    if (tid < 128) mk[tid] = mask[(size_t)b * P + q0 + tid];
    __syncthreads();

    int w = tid >> 6, lane = tid & 63;
    int quad = lane >> 4, mrow = lane & 15;
    int nrt = (ncnt + 15) >> 4;

    for (int rt = w; rt < nrt; rt += 4){
        int i = rt * 16 + mrow;
        int prow = needlist[(size_t)b * P + ((i < ncnt) ? i : (ncnt - 1))];
        const u16* ab = &boxi[((size_t)b * P + prow) * H128];
        short8_t af[4];
        #pragma unroll
        for (int kt = 0; kt < 4; kt++)
            af[kt] = *(const short8_t*)&ab[(kt * 4 + quad) * 8];

        float se[4] = {0.f, 0.f, 0.f, 0.f};
        #pragma unroll
        for (int nt = 0; nt < 8; nt++){
            int cl = nt * 16 + mrow;
            f32x4_t acc = (f32x4_t){0.f, 0.f, 0.f, 0.f};
            #pragma unroll
            for (int kt = 0; kt < 4; kt++){
                int chunk = kt * 4 + quad;
                short8_t bf = *(const short8_t*)&Bs[cl * H128 + ((chunk ^ mrow) * 8)];
                acc = __builtin_amdgcn_mfma_f32_16x16x32_bf16(af[kt], bf, acc, 0, 0, 0);
            }
            float m = mk[cl] ? 1.f : 0.f;
            #pragma unroll
            for (int reg = 0; reg < 4; reg++) se[reg] += m * __expf(acc[reg]);
        }
        #pragma unroll
        for (int off = 1; off <= 8; off <<= 1)
            #pragma unroll
            for (int reg = 0; reg < 4; reg++) se[reg] += __shfl_xor(se[reg], off);
        if (mrow == 0){
            #pragma unroll
            for (int reg = 0; reg < 4; reg++){
                int i2 = rt * 16 + quad * 4 + reg;
                if (i2 < ncnt)
                    atomicAdd(&lse[(size_t)b * P + needlist[(size_t)b * P + i2]], se[reg]);
            }
        }
    }
}

// ---------------- K7: per (b,l) — lang finalize + iou NCE (ballot compaction) ----------------
__global__ void __launch_bounds__(256) k_iou(
        const u16* __restrict__ boxi, const u8* __restrict__ tgt,
        const float* __restrict__ lse, const float* __restrict__ cnt,
        const float* __restrict__ tcnt, const float* __restrict__ sexp,
        const float* __restrict__ sdot, const int* __restrict__ lni,
        float* __restrict__ accf, int b0, int P, int L)
{
    int blk = blockIdx.x, b = blk / L, l = blk % L, tid = threadIdx.x;
    if (l >= lni[b0 + b]) return;
    float tf = tcnt[b * L + l];
    if (tf <= 0.f) return;
    float c1 = fmaxf(cnt[b], 1.f);

    if (tid == 0){
        float LSE = logf(fmaxf(sexp[b * L + l], 1e-30f));
        atomicAdd(&accf[0], clampf(0.5f * (tf * LSE - sdot[b * L + l]) / c1, -1e5f, 1e5f));
    }

    int wid = tid >> 6, lane = tid & 63;
    __shared__ int mem[1024];
    __shared__ int wbase[4];
    __shared__ int total;
    __shared__ float redu[256];
    __shared__ float Ufin;
    if (tid == 0) total = 0;
    __syncthreads();
    for (int k = 0; k < P / 256; k++){
        int p = tid + k * 256;
        bool hit = (tgt[((size_t)b * L + l) * P + p] != 0);
        u64 bal = __ballot(hit);
        if (lane == 0) wbase[wid] = __popcll(bal);
        __syncthreads();
        if (tid == 0){
            int s = total;
            for (int w = 0; w < 4; w++){ int c = wbase[w]; wbase[w] = s; s += c; }
            total = s;
        }
        __syncthreads();
        if (hit){
            int rank = __popcll(bal & ((1ULL << lane) - 1ULL));
            mem[wbase[wid] + rank] = p;
        }
        __syncthreads();
    }
    int t = total;

    float U = 0.f;
    for (int i = tid; i < t; i += 256)
        U += logf(fmaxf(lse[(size_t)b * P + mem[i]], 1e-30f));
    redu[tid] = U; __syncthreads();
    for (int st = 128; st > 0; st >>= 1){
        if (tid < st) redu[tid] += redu[tid + st];
        __syncthreads();
    }
    if (tid == 0) Ufin = redu[0];
    __syncthreads();

    // sum over targets of boxi rows, then squared-norm; 2 partials per h-dim
    {
        int h = tid & 127, half = tid >> 7;
        float vh = 0.f;
        for (int i = half; i < t; i += 2)
            vh += bf2f(boxi[((size_t)b * P + mem[i]) * H128 + h]);
        redu[tid] = vh;
    }
    __syncthreads();
    if (tid < 128){
        float v = redu[tid] + redu[tid + 128];
        redu[tid] = v * v;
    }
    __syncthreads();
    for (int st = 64; st > 0; st >>= 1){
        if (tid < st) redu[tid] += redu[tid + st];
        __syncthreads();
    }
    if (tid == 0)
        atomicAdd(&accf[1], clampf(((float)t * Ufin - redu[0]) / (c1 * c1), -1e5f, 1e5f));
}

// ---------------- K8: finalize ----------------
__global__ void k_fin(const float* __restrict__ accf, const int* __restrict__ flagp,
                      void* __restrict__ out, float invB)
{
    if (threadIdx.x == 0 && blockIdx.x == 0){
        float a = clampf(accf[0] * invB, -1e6f, 1e6f);
        float b = clampf(accf[1] * invB, -1e6f, 1e6f);
        if (*flagp){
            ((float*)out)[0] = a; ((float*)out)[1] = b;
        } else {
            ((u16*)out)[0] = f2bf(a); ((u16*)out)[1] = f2bf(b);
        }
    }
}

extern "C" void kernel_launch(void* const* d_in, const int* in_sizes, int n_in,
                              void* d_out, int out_size, void* d_ws, size_t ws_size,
                              hipStream_t stream)
{
    const void* pred_center = d_in[0];
    const void* pred_size   = d_in[1];
    const void* bbox        = d_in[2];
    const void* gtc         = d_in[3];
    const void* gts         = d_in[4];
    const void* lang        = d_in[5];
    const void* obj         = d_in[6];
    const void* Wt          = d_in[7];
    const void* Wp          = d_in[8];
    const void* Wpi         = d_in[9];
    const int*  lang_raw    = (const int*)d_in[10];

    int B = in_sizes[10];
    int P = in_sizes[0] / (3 * B);
    int L = in_sizes[3] / (3 * B);
    (void)n_in; (void)out_size;

    char* w = (char*)d_ws;
    float* accf  = (float*)w;
    int*   flagp = (int*)(w + 64);
    int*   lni   = (int*)(w + 256);
    char*  chunk_base = w + 512;
    size_t chunk_avail = (ws_size > 512) ? ws_size - 512 : 0;

    size_t per_b = (size_t)P + (size_t)P * 4 + 8 + (size_t)L * 4 * 3
                 + (size_t)L * P + (size_t)P * 4
                 + (size_t)P * H128 * 2 * 2 + (size_t)L * H128 * 2;
    size_t slop = 14 * 256;
    int C = B;
    if ((size_t)B * per_b + slop > chunk_avail){
        size_t av = (chunk_avail > slop) ? chunk_avail - slop : 0;
        C = (int)(av / per_b);
        if (C < 1) C = 1;
        if (C > B) C = B;
    }

    k_init<<<1, 64, 0, stream>>>(lang_raw, pred_size, lni, accf, flagp, B);

    for (int b0 = 0; b0 < B; b0 += C){
        int c = (B - b0 < C) ? (B - b0) : C;

        size_t off = 0;
        auto carve = [&](size_t bytes) -> void* {
            void* p = chunk_base + off;
            off = (off + bytes + 255) & ~(size_t)255;
            return p;
        };
        u8*    mask     = (u8*)   carve((size_t)c * P);
        float* cnt      = (float*)carve((size_t)c * 4);
        int*   needcnt  = (int*)  carve((size_t)c * 4);
        float* tcnt     = (float*)carve((size_t)c * L * 4);
        float* sexp     = (float*)carve((size_t)c * L * 4);
        float* sdot     = (float*)carve((size_t)c * L * 4);
        u8*    tgtb     = (u8*)   carve((size_t)c * L * P);
        int*   needlist = (int*)  carve((size_t)c * P * 4);
        float* lse      = (float*)carve((size_t)c * P * 4);
        u16*   boxl     = (u16*)  carve((size_t)c * P * H128 * 2);
        u16*   boxi     = (u16*)  carve((size_t)c * P * H128 * 2);
        u16*   text     = (u16*)  carve((size_t)c * L * H128 * 2);

        k_meta<<<c, 256, 0, stream>>>(obj, flagp, mask, cnt, b0, P);
        k_tgt <<<c * L, 256, 0, stream>>>(gtc, gts, pred_center, pred_size, flagp,
                                          mask, tgtb, tcnt, sexp, sdot, b0, P, L);
        k_need<<<c, 256, 0, stream>>>(tgtb, needcnt, needlist, lse, P, L);
        int nb1 = (c * P + 63) / 64;
        int nbt = (c * L + 63) / 64;
        k_proj<<<2 * nb1 + nbt, 256, 0, stream>>>(bbox, lang, Wp, Wpi, Wt, flagp,
                                                  boxl, boxi, text, nb1,
                                                  b0 * P, b0 * L, c * P, c * L);
        k_lang<<<c * (P / 128), 256, 0, stream>>>(text, boxl, mask, tgtb, sexp, sdot, P, L);
        k_lse <<<c * (P / 128), 256, 0, stream>>>(boxi, mask, needcnt, needlist, lse, P);
        k_iou <<<c * L, 256, 0, stream>>>(boxi, tgtb, lse, cnt, tcnt, sexp, sdot,
                                          lni, accf, b0, P, L);
    }

    k_fin<<<1, 64, 0, stream>>>(accf, flagp, d_out, 1.0f / (float)B);
}

// Round 9
// 133.641 us; speedup vs baseline: 2.3306x; 1.2630x over previous
//
#include <hip/hip_runtime.h>
#include <hip/hip_bf16.h>
#include <math.h>

typedef unsigned short u16;
typedef unsigned int   u32;
typedef unsigned char  u8;
typedef unsigned long long u64;

typedef __attribute__((ext_vector_type(8))) short short8_t;
typedef __attribute__((ext_vector_type(4))) float f32x4_t;

#define H128 128

__device__ __forceinline__ float bf2f(u16 v){
    u32 u = ((u32)v) << 16;
    return __uint_as_float(u);
}
__device__ __forceinline__ u16 f2bf(float x){
    u32 u = __float_as_uint(x);
    u32 r = (u + 0x7fffu + ((u >> 16) & 1u)) >> 16;
    return (u16)r;
}
__device__ __forceinline__ void unpack8(uint4 v, float* f){
    f[0] = bf2f((u16)(v.x & 0xffff)); f[1] = bf2f((u16)(v.x >> 16));
    f[2] = bf2f((u16)(v.y & 0xffff)); f[3] = bf2f((u16)(v.y >> 16));
    f[4] = bf2f((u16)(v.z & 0xffff)); f[5] = bf2f((u16)(v.z >> 16));
    f[6] = bf2f((u16)(v.w & 0xffff)); f[7] = bf2f((u16)(v.w >> 16));
}
__device__ __forceinline__ float ld1(const void* p, size_t i, int F){
    return F ? ((const float*)p)[i] : bf2f(((const u16*)p)[i]);
}
__device__ __forceinline__ void ld8(const void* p, size_t i, int F, float* f){
    if (F){
        const float* fp = (const float*)p + i;
        float4 a = *(const float4*)fp;
        float4 b = *(const float4*)(fp + 4);
        f[0]=a.x; f[1]=a.y; f[2]=a.z; f[3]=a.w;
        f[4]=b.x; f[5]=b.y; f[6]=b.z; f[7]=b.w;
    } else {
        uint4 v = *(const uint4*)((const u16*)p + i);
        unpack8(v, f);
    }
}
__device__ __forceinline__ float clampf(float x, float lo, float hi){
    return fminf(fmaxf(x, lo), hi);
}

// ================= D0: zero + once-per-call init =================
__global__ void __launch_bounds__(256) k_zero(
        const int* __restrict__ lang_raw, const void* __restrict__ pred_size,
        int* __restrict__ lni, float* __restrict__ accf, int* __restrict__ flagp,
        u32* __restrict__ ctrs,
        float* __restrict__ cnt, float* __restrict__ tcnt, float* __restrict__ sexp,
        float* __restrict__ sdot, float* __restrict__ lse, int* __restrict__ needcnt,
        int B, int c, int P, int L, int first)
{
    int gid = blockIdx.x * 256 + threadIdx.x;
    int gsz = gridDim.x * 256;
    for (int i = gid; i < c * P; i += gsz) lse[i] = 0.f;
    for (int i = gid; i < c * L; i += gsz){ tcnt[i] = 0.f; sexp[i] = 0.f; sdot[i] = 0.f; }
    for (int i = gid; i < c; i += gsz){ cnt[i] = 0.f; needcnt[i] = 0; }
    if (first && blockIdx.x == 0){
        int tid = threadIdx.x;
        __shared__ int cir, is64_s;
        if (tid == 0){ cir = 0; accf[0] = 0.f; accf[1] = 0.f; }
        __syncthreads();
        if (tid < 64){
            const u16* ps = (const u16*)pred_size;
            int cc = 0;
            u16 v0 = ps[tid], v1 = ps[tid + 64];
            if (v0 >= 0x3000 && v0 < 0x4100) cc++;
            if (v1 >= 0x3000 && v1 < 0x4100) cc++;
            atomicAdd(&cir, cc);
        }
        if (tid < 64) ctrs[tid] = 0u;
        if (tid == 0)
            is64_s = ((B >= 8) && lang_raw[1] == 0 && lang_raw[3] == 0 &&
                      lang_raw[5] == 0 && lang_raw[7] == 0) ? 1 : 0;
        __syncthreads();
        if (tid == 0) *flagp = (cir >= 120) ? 0 : 1;   // 0 = bf16, 1 = f32
        if (tid < B) lni[tid] = is64_s ? lang_raw[2 * tid] : lang_raw[tid];
    }
}

// ================= D1: prep (mask+iou/tgt+needlist) fused with proj =================
__device__ void prep_fn(char* smem,
        const void* obj, const void* gtc, const void* gts,
        const void* pc_, const void* ps_, int F,
        u8* mask, float* cnt, u8* tgt, float* tcnt,
        int* needcnt, int* needlist, int b0, int P, int L, int bblk)
{
    int tid = threadIdx.x;
    int nt = P / 256;
    int b = bblk / nt, ct = bblk % nt;
    int p = ct * 256 + tid;

    float* gtb = (float*)smem;                       // [L][8]: gmin0..2,gmax0..2,volg
    float* tl  = (float*)(smem + L * 32);            // [L] per-l local target count
    float* red = (float*)(smem + L * 32 + L * 4);    // [256]

    if (tid < L){
        float gmn[3], gmx[3], gss[3];
        for (int i = 0; i < 3; i++){
            size_t gi = ((size_t)(b0 + b) * L + tid) * 3 + i;
            float gc  = ld1(gtc, gi, F);
            float gsv = ld1(gts, gi, F) + 0.01f;
            gmn[i] = gc - 0.5f * gsv; gmx[i] = gc + 0.5f * gsv; gss[i] = gsv;
        }
        float* r = &gtb[tid * 8];
        r[0] = gmn[0]; r[1] = gmn[1]; r[2] = gmn[2];
        r[3] = gmx[0]; r[4] = gmx[1]; r[5] = gmx[2];
        r[6] = gss[0] * gss[1] * gss[2];
        tl[tid] = 0.f;
    }
    __syncthreads();

    size_t ob = ((size_t)(b0 + b) * P + p) * 2;
    float s0 = ld1(obj, ob, F), s1 = ld1(obj, ob + 1, F);
    u8 m = (s1 > s0) ? 1 : 0;
    mask[(size_t)b * P + p] = m;

    size_t pb = ((size_t)(b0 + b) * P + p) * 3;
    float pl[3], ph[3], volp = 1.f;
    for (int i = 0; i < 3; i++){
        float pcv = ld1(pc_, pb + i, F), psv = ld1(ps_, pb + i, F);
        pl[i] = pcv - 0.5f * psv; ph[i] = pcv + 0.5f * psv; volp *= psv;
    }
    bool any = false;
    for (int l = 0; l < L; l++){
        float* r = &gtb[l * 8];
        float inter = 1.f;
        for (int i = 0; i < 3; i++){
            float mn = fmaxf(r[i],     pl[i]);
            float mx = fminf(r[3 + i], ph[i]);
            inter *= fmaxf(mx - mn, 0.f);
        }
        float iou = inter / (r[6] + volp - inter + 1e-7f);
        u8 t = (iou > 0.25f && m) ? 1 : 0;
        tgt[((size_t)b * L + l) * P + p] = t;
        if (t){ any = true; atomicAdd(&tl[l], 1.f); }
    }
    // wave-level needlist compaction (order within list is irrelevant)
    int lane = tid & 63;
    u64 bal = __ballot(any);
    int wcount = __popcll(bal);
    int base = 0;
    if (lane == 0 && wcount) base = atomicAdd(&needcnt[b], wcount);
    base = __shfl(base, 0);
    if (any){
        int rank = __popcll(bal & ((1ULL << lane) - 1ULL));
        needlist[(size_t)b * P + base + rank] = p;
    }
    // cnt block-reduce then one atomic
    red[tid] = (float)m;
    __syncthreads();
    for (int st = 128; st > 0; st >>= 1){
        if (tid < st) red[tid] += red[tid + st];
        __syncthreads();
    }
    if (tid == 0) atomicAdd(&cnt[b], red[0]);
    if (tid < L && tl[tid] != 0.f) atomicAdd(&tcnt[b * L + tid], tl[tid]);
}

__device__ void proj_fn(char* smem,
        const void* __restrict__ X, const void* __restrict__ W, int F,
        u16* __restrict__ outb, int row0, int rowoff, int nrows)
{
    int tid = threadIdx.x;
    u16* Ws = (u16*)smem;                 // 128*128*2 = 32768
    u16* Xs = (u16*)(smem + 32768);       // 64*128*2  = 16384

    for (int i = 0; i < 8; i++){
        int cid = tid + i * 256;
        int r = cid >> 4, cc = cid & 15;
        float f[8];
        ld8(W, (size_t)r * H128 + cc * 8, F, f);
        u16* dst = &Ws[r * H128 + ((cc ^ (r & 15)) * 8)];
        #pragma unroll
        for (int j = 0; j < 8; j++) dst[j] = f2bf(f[j]);
    }
    for (int i = 0; i < 4; i++){
        int cid = tid + i * 256;
        int r = cid >> 4, cc = cid & 15;
        int row = row0 + r;
        float f[8];
        if (row < nrows){
            ld8(X, (size_t)(rowoff + row) * H128 + cc * 8, F, f);
        } else {
            for (int j = 0; j < 8; j++) f[j] = 0.f;
        }
        u16* dst = &Xs[r * H128 + ((cc ^ (r & 15)) * 8)];
        #pragma unroll
        for (int j = 0; j < 8; j++) dst[j] = f2bf(f[j]);
    }
    __syncthreads();

    int w = tid >> 6, lane = tid & 63;
    int quad = lane >> 4, mrow = lane & 15;

    short8_t af[4];
    int arow = w * 16 + mrow;
    #pragma unroll
    for (int kt = 0; kt < 4; kt++){
        int chunk = kt * 4 + quad;
        af[kt] = *(const short8_t*)&Xs[arow * H128 + ((chunk ^ mrow) * 8)];
    }

    f32x4_t acc[8];
    #pragma unroll
    for (int ntl = 0; ntl < 8; ntl++) acc[ntl] = (f32x4_t){0.f, 0.f, 0.f, 0.f};
    #pragma unroll
    for (int ntl = 0; ntl < 8; ntl++){
        int n = ntl * 16 + mrow;
        #pragma unroll
        for (int kt = 0; kt < 4; kt++){
            int chunk = kt * 4 + quad;
            short8_t bf = *(const short8_t*)&Ws[n * H128 + ((chunk ^ mrow) * 8)];
            acc[ntl] = __builtin_amdgcn_mfma_f32_16x16x32_bf16(af[kt], bf, acc[ntl], 0, 0, 0);
        }
    }

    float ss[4] = {0.f, 0.f, 0.f, 0.f};
    #pragma unroll
    for (int ntl = 0; ntl < 8; ntl++)
        #pragma unroll
        for (int reg = 0; reg < 4; reg++) ss[reg] += acc[ntl][reg] * acc[ntl][reg];
    #pragma unroll
    for (int off = 1; off <= 8; off <<= 1)
        #pragma unroll
        for (int reg = 0; reg < 4; reg++) ss[reg] += __shfl_xor(ss[reg], off);
    float rn[4];
    #pragma unroll
    for (int reg = 0; reg < 4; reg++) rn[reg] = 1.0f / fmaxf(sqrtf(ss[reg]), 1e-12f);

    #pragma unroll
    for (int reg = 0; reg < 4; reg++){
        int row = row0 + w * 16 + quad * 4 + reg;
        if (row < nrows){
            #pragma unroll
            for (int ntl = 0; ntl < 8; ntl++){
                int col = ntl * 16 + mrow;
                outb[(size_t)row * H128 + col] = f2bf(acc[ntl][reg] * rn[reg]);
            }
        }
    }
}

__global__ void __launch_bounds__(256) k_main1(
        const void* __restrict__ obj, const void* __restrict__ gtc, const void* __restrict__ gts,
        const void* __restrict__ pc_, const void* __restrict__ ps_,
        const void* __restrict__ bbox, const void* __restrict__ lang,
        const void* __restrict__ Wp, const void* __restrict__ Wpi, const void* __restrict__ Wt,
        const int* __restrict__ Fp,
        u8* __restrict__ mask, float* __restrict__ cnt, u8* __restrict__ tgt,
        float* __restrict__ tcnt, int* __restrict__ needcnt, int* __restrict__ needlist,
        u16* __restrict__ boxl, u16* __restrict__ boxi, u16* __restrict__ text,
        int nprep, int nb1, int b0, int P, int L, int nrows_bp, int nrows_t)
{
    __shared__ __align__(16) char smem[49152];
    const int F = *Fp;
    int blk = blockIdx.x;
    if (blk < nprep){
        prep_fn(smem, obj, gtc, gts, pc_, ps_, F, mask, cnt, tgt, tcnt,
                needcnt, needlist, b0, P, L, blk);
        return;
    }
    blk -= nprep;
    if (blk < nb1)
        proj_fn(smem, bbox, Wp,  F, boxl, blk * 64,            b0 * P, nrows_bp);
    else if (blk < 2 * nb1)
        proj_fn(smem, bbox, Wpi, F, boxi, (blk - nb1) * 64,    b0 * P, nrows_bp);
    else
        proj_fn(smem, lang, Wt,  F, text, (blk - 2 * nb1) * 64, b0 * L, nrows_t);
}

// ================= D2: lang-GEMM fused with lse-GEMM =================
__device__ void lang_fn(char* smem,
        const u16* __restrict__ text, const u16* __restrict__ boxl,
        const u8* __restrict__ mask, const u8* __restrict__ tgt,
        float* __restrict__ sexp, float* __restrict__ sdot, int P, int L, int bblk)
{
    int nct = P >> 7;
    int b = bblk / nct, ct = bblk % nct;
    int p0 = ct * 128;
    int tid = threadIdx.x;

    u16* As = (u16*)smem;                 // 8192
    u16* Bs = (u16*)(smem + 8192);        // 32768
    u8*  Ts = (u8*)(smem + 40960);        // 4096
    u8*  mk = (u8*)(smem + 45056);        // 128

    for (int i = 0; i < 2; i++){
        int cid = tid + i * 256;
        int r = cid >> 4, cc = cid & 15;
        uint4 v = *(const uint4*)&text[((size_t)b * L + r) * H128 + cc * 8];
        *(uint4*)&As[r * H128 + ((cc ^ (r & 15)) * 8)] = v;
    }
    for (int i = 0; i < 8; i++){
        int cid = tid + i * 256;
        int r = cid >> 4, cc = cid & 15;
        uint4 v = *(const uint4*)&boxl[((size_t)b * P + p0 + r) * H128 + cc * 8];
        *(uint4*)&Bs[r * H128 + ((cc ^ (r & 15)) * 8)] = v;
    }
    {
        int l = tid >> 3, seg = tid & 7;
        uint4 v = *(const uint4*)&tgt[((size_t)b * L + l) * P + p0 + seg * 16];
        *(uint4*)&Ts[l * 128 + seg * 16] = v;
    }
    if (tid < 128) mk[tid] = mask[(size_t)b * P + p0 + tid];
    __syncthreads();

    int w = tid >> 6, lane = tid & 63;
    int quad = lane >> 4, mrow = lane & 15;
    int mt = w & 1, ch = w >> 1;

    short8_t af[4];
    #pragma unroll
    for (int kt = 0; kt < 4; kt++){
        int chunk = kt * 4 + quad;
        af[kt] = *(const short8_t*)&As[(mt * 16 + mrow) * H128 + ((chunk ^ mrow) * 8)];
    }

    float se[4] = {0.f, 0.f, 0.f, 0.f};
    float sd[4] = {0.f, 0.f, 0.f, 0.f};
    #pragma unroll
    for (int nt = 0; nt < 4; nt++){
        int cl = ch * 64 + nt * 16 + mrow;
        f32x4_t acc = (f32x4_t){0.f, 0.f, 0.f, 0.f};
        #pragma unroll
        for (int kt = 0; kt < 4; kt++){
            int chunk = kt * 4 + quad;
            short8_t bf = *(const short8_t*)&Bs[cl * H128 + ((chunk ^ mrow) * 8)];
            acc = __builtin_amdgcn_mfma_f32_16x16x32_bf16(af[kt], bf, acc, 0, 0, 0);
        }
        float m = mk[cl] ? 1.f : 0.f;
        #pragma unroll
        for (int reg = 0; reg < 4; reg++){
            int l = mt * 16 + quad * 4 + reg;
            float d = acc[reg];
            se[reg] += m * __expf(d);
            if (m != 0.f && Ts[l * 128 + cl]) sd[reg] += d;
        }
    }
    #pragma unroll
    for (int off = 1; off <= 8; off <<= 1)
        #pragma unroll
        for (int reg = 0; reg < 4; reg++){
            se[reg] += __shfl_xor(se[reg], off);
            sd[reg] += __shfl_xor(sd[reg], off);
        }
    if (mrow == 0){
        #pragma unroll
        for (int reg = 0; reg < 4; reg++){
            int l = mt * 16 + quad * 4 + reg;
            atomicAdd(&sexp[b * L + l], se[reg]);
            atomicAdd(&sdot[b * L + l], sd[reg]);
        }
    }
}

__device__ void lse_fn(char* smem,
        const u16* __restrict__ boxi, const u8* __restrict__ mask,
        const int* __restrict__ needcnt, const int* __restrict__ needlist,
        float* __restrict__ lse, int P, int bblk)
{
    int nct = P >> 7;
    int b = bblk / nct, ct = bblk % nct;
    int q0 = ct * 128;
    int ncnt = needcnt[b];
    if (ncnt <= 0) return;
    int tid = threadIdx.x;

    u16* Bs = (u16*)smem;               // 32768
    u8*  mk = (u8*)(smem + 32768);      // 128

    for (int i = 0; i < 8; i++){
        int cid = tid + i * 256;
        int r = cid >> 4, cc = cid & 15;
        uint4 v = *(const uint4*)&boxi[((size_t)b * P + q0 + r) * H128 + cc * 8];
        *(uint4*)&Bs[r * H128 + ((cc ^ (r & 15)) * 8)] = v;
    }
    if (tid < 128) mk[tid] = mask[(size_t)b * P + q0 + tid];
    __syncthreads();

    int w = tid >> 6, lane = tid & 63;
    int quad = lane >> 4, mrow = lane & 15;
    int nrt = (ncnt + 15) >> 4;

    for (int rt = w; rt < nrt; rt += 4){
        int i = rt * 16 + mrow;
        int prow = needlist[(size_t)b * P + ((i < ncnt) ? i : (ncnt - 1))];
        const u16* ab = &boxi[((size_t)b * P + prow) * H128];
        short8_t af[4];
        #pragma unroll
        for (int kt = 0; kt < 4; kt++)
            af[kt] = *(const short8_t*)&ab[(kt * 4 + quad) * 8];

        float se[4] = {0.f, 0.f, 0.f, 0.f};
        #pragma unroll
        for (int nt = 0; nt < 8; nt++){
            int cl = nt * 16 + mrow;
            f32x4_t acc = (f32x4_t){0.f, 0.f, 0.f, 0.f};
            #pragma unroll
            for (int kt = 0; kt < 4; kt++){
                int chunk = kt * 4 + quad;
                short8_t bf = *(const short8_t*)&Bs[cl * H128 + ((chunk ^ mrow) * 8)];
                acc = __builtin_amdgcn_mfma_f32_16x16x32_bf16(af[kt], bf, acc, 0, 0, 0);
            }
            float m = mk[cl] ? 1.f : 0.f;
            #pragma unroll
            for (int reg = 0; reg < 4; reg++) se[reg] += m * __expf(acc[reg]);
        }
        #pragma unroll
        for (int off = 1; off <= 8; off <<= 1)
            #pragma unroll
            for (int reg = 0; reg < 4; reg++) se[reg] += __shfl_xor(se[reg], off);
        if (mrow == 0){
            #pragma unroll
            for (int reg = 0; reg < 4; reg++){
                int i2 = rt * 16 + quad * 4 + reg;
                if (i2 < ncnt)
                    atomicAdd(&lse[(size_t)b * P + needlist[(size_t)b * P + i2]], se[reg]);
            }
        }
    }
}

__global__ void __launch_bounds__(256) k_main2(
        const u16* __restrict__ text, const u16* __restrict__ boxl, const u16* __restrict__ boxi,
        const u8* __restrict__ mask, const u8* __restrict__ tgt,
        const int* __restrict__ needcnt, const int* __restrict__ needlist,
        float* __restrict__ sexp, float* __restrict__ sdot, float* __restrict__ lse,
        int nlang, int P, int L)
{
    __shared__ __align__(16) char smem[45184];
    int blk = blockIdx.x;
    if (blk < nlang) lang_fn(smem, text, boxl, mask, tgt, sexp, sdot, P, L, blk);
    else             lse_fn(smem, boxi, mask, needcnt, needlist, lse, P, blk - nlang);
}

// ================= D3: iou NCE + lang finalize + device-side output write =================
__global__ void __launch_bounds__(256) k_main3(
        const u16* __restrict__ boxi, const u8* __restrict__ tgt,
        const float* __restrict__ lse, const float* __restrict__ cnt,
        const float* __restrict__ tcnt, const float* __restrict__ sexp,
        const float* __restrict__ sdot, const int* __restrict__ lni,
        float* __restrict__ accf, u32* __restrict__ ctr, const int* __restrict__ flagp,
        void* __restrict__ out, float invB, int is_last, int b0, int P, int L)
{
    int blk = blockIdx.x, b = blk / L, l = blk % L, tid = threadIdx.x;
    float tf = tcnt[b * L + l];
    bool active = (l < lni[b0 + b]) && (tf > 0.f);

    if (active){
        float c1 = fmaxf(cnt[b], 1.f);
        if (tid == 0){
            float LSE = logf(fmaxf(sexp[b * L + l], 1e-30f));
            atomicAdd(&accf[0], clampf(0.5f * (tf * LSE - sdot[b * L + l]) / c1, -1e5f, 1e5f));
        }
        int wid = tid >> 6, lane = tid & 63;
        __shared__ int mem[1024];
        __shared__ int wbase[4];
        __shared__ int total;
        __shared__ float redu[256];
        __shared__ float Ufin;
        if (tid == 0) total = 0;
        __syncthreads();
        for (int k = 0; k < P / 256; k++){
            int p = tid + k * 256;
            bool hit = (tgt[((size_t)b * L + l) * P + p] != 0);
            u64 bal = __ballot(hit);
            if (lane == 0) wbase[wid] = __popcll(bal);
            __syncthreads();
            if (tid == 0){
                int s = total;
                for (int w = 0; w < 4; w++){ int c = wbase[w]; wbase[w] = s; s += c; }
                total = s;
            }
            __syncthreads();
            if (hit){
                int rank = __popcll(bal & ((1ULL << lane) - 1ULL));
                mem[wbase[wid] + rank] = p;
            }
            __syncthreads();
        }
        int t = total;

        float U = 0.f;
        for (int i = tid; i < t; i += 256)
            U += logf(fmaxf(lse[(size_t)b * P + mem[i]], 1e-30f));
        redu[tid] = U; __syncthreads();
        for (int st = 128; st > 0; st >>= 1){
            if (tid < st) redu[tid] += redu[tid + st];
            __syncthreads();
        }
        if (tid == 0) Ufin = redu[0];
        __syncthreads();

        {
            int h = tid & 127, half = tid >> 7;
            float vh = 0.f;
            for (int i = half; i < t; i += 2)
                vh += bf2f(boxi[((size_t)b * P + mem[i]) * H128 + h]);
            redu[tid] = vh;
        }
        __syncthreads();
        if (tid < 128){
            float v = redu[tid] + redu[tid + 128];
            redu[tid] = v * v;
        }
        __syncthreads();
        for (int st = 64; st > 0; st >>= 1){
            if (tid < st) redu[tid] += redu[tid + st];
            __syncthreads();
        }
        if (tid == 0)
            atomicAdd(&accf[1], clampf(((float)t * Ufin - redu[0]) / (c1 * c1), -1e5f, 1e5f));
    }

    // common tail: counter; last block of last chunk writes output
    if (tid == 0){
        __threadfence();
        u32 old = atomicAdd(ctr, 1u);
        if (is_last && old == (u32)(gridDim.x - 1)){
            __threadfence();
            float a  = clampf(accf[0] * invB, -1e6f, 1e6f);
            float bb = clampf(accf[1] * invB, -1e6f, 1e6f);
            if (*flagp){
                ((float*)out)[0] = a; ((float*)out)[1] = bb;
            } else {
                ((u16*)out)[0] = f2bf(a); ((u16*)out)[1] = f2bf(bb);
            }
        }
    }
}

extern "C" void kernel_launch(void* const* d_in, const int* in_sizes, int n_in,
                              void* d_out, int out_size, void* d_ws, size_t ws_size,
                              hipStream_t stream)
{
    const void* pred_center = d_in[0];
    const void* pred_size   = d_in[1];
    const void* bbox        = d_in[2];
    const void* gtc         = d_in[3];
    const void* gts         = d_in[4];
    const void* lang        = d_in[5];
    const void* obj         = d_in[6];
    const void* Wt          = d_in[7];
    const void* Wp          = d_in[8];
    const void* Wpi         = d_in[9];
    const int*  lang_raw    = (const int*)d_in[10];

    int B = in_sizes[10];
    int P = in_sizes[0] / (3 * B);
    int L = in_sizes[3] / (3 * B);
    (void)n_in; (void)out_size;

    char* w = (char*)d_ws;
    float* accf  = (float*)w;
    int*   flagp = (int*)(w + 64);
    u32*   ctrs  = (u32*)(w + 128);      // 64 chunk counters (256 B)
    int*   lni   = (int*)(w + 384);
    char*  chunk_base = w + 768;
    size_t chunk_avail = (ws_size > 768) ? ws_size - 768 : 0;

    size_t per_b = (size_t)P + (size_t)P * 4 + 8 + (size_t)L * 4 * 3
                 + (size_t)L * P + (size_t)P * 4
                 + (size_t)P * H128 * 2 * 2 + (size_t)L * H128 * 2;
    size_t slop = 14 * 256;
    int C = B;
    if ((size_t)B * per_b + slop > chunk_avail){
        size_t av = (chunk_avail > slop) ? chunk_avail - slop : 0;
        C = (int)(av / per_b);
        if (C < 1) C = 1;
        if (C > B) C = B;
    }

    int chunk_idx = 0;
    for (int b0 = 0; b0 < B; b0 += C, chunk_idx++){
        int c = (B - b0 < C) ? (B - b0) : C;

        size_t off = 0;
        auto carve = [&](size_t bytes) -> void* {
            void* p = chunk_base + off;
            off = (off + bytes + 255) & ~(size_t)255;
            return p;
        };
        u8*    mask     = (u8*)   carve((size_t)c * P);
        float* cnt      = (float*)carve((size_t)c * 4);
        int*   needcnt  = (int*)  carve((size_t)c * 4);
        float* tcnt     = (float*)carve((size_t)c * L * 4);
        float* sexp     = (float*)carve((size_t)c * L * 4);
        float* sdot     = (float*)carve((size_t)c * L * 4);
        u8*    tgtb     = (u8*)   carve((size_t)c * L * P);
        int*   needlist = (int*)  carve((size_t)c * P * 4);
        float* lse      = (float*)carve((size_t)c * P * 4);
        u16*   boxl     = (u16*)  carve((size_t)c * P * H128 * 2);
        u16*   boxi     = (u16*)  carve((size_t)c * P * H128 * 2);
        u16*   text     = (u16*)  carve((size_t)c * L * H128 * 2);

        int is_last = (b0 + c >= B) ? 1 : 0;

        k_zero<<<32, 256, 0, stream>>>(lang_raw, pred_size, lni, accf, flagp, ctrs,
                                       cnt, tcnt, sexp, sdot, lse, needcnt,
                                       B, c, P, L, (b0 == 0) ? 1 : 0);

        int nprep = c * (P / 256);
        int nb1 = (c * P + 63) / 64;
        int nbt = (c * L + 63) / 64;
        k_main1<<<nprep + 2 * nb1 + nbt, 256, 0, stream>>>(
            obj, gtc, gts, pred_center, pred_size, bbox, lang, Wp, Wpi, Wt, flagp,
            mask, cnt, tgtb, tcnt, needcnt, needlist, boxl, boxi, text,
            nprep, nb1, b0, P, L, c * P, c * L);

        int nlang = c * (P / 128);
        k_main2<<<2 * nlang, 256, 0, stream>>>(text, boxl, boxi, mask, tgtb,
                                               needcnt, needlist, sexp, sdot, lse,
                                               nlang, P, L);

        k_main3<<<c * L, 256, 0, stream>>>(boxi, tgtb, lse, cnt, tcnt, sexp, sdot,
                                           lni, accf, &ctrs[chunk_idx], flagp, d_out,
                                           1.0f / (float)B, is_last, b0, P, L);
    }
}

// Round 10
// 133.542 us; speedup vs baseline: 2.3324x; 1.0007x over previous
//
#include <hip/hip_runtime.h>
#include <hip/hip_bf16.h>
#include <math.h>

typedef unsigned short u16;
typedef unsigned int   u32;
typedef unsigned char  u8;
typedef unsigned long long u64;

typedef __attribute__((ext_vector_type(8))) short short8_t;
typedef __attribute__((ext_vector_type(4))) float f32x4_t;

#define H128 128

__device__ __forceinline__ float bf2f(u16 v){
    u32 u = ((u32)v) << 16;
    return __uint_as_float(u);
}
__device__ __forceinline__ u16 f2bf(float x){
    u32 u = __float_as_uint(x);
    u32 r = (u + 0x7fffu + ((u >> 16) & 1u)) >> 16;
    return (u16)r;
}
__device__ __forceinline__ void unpack8(uint4 v, float* f){
    f[0] = bf2f((u16)(v.x & 0xffff)); f[1] = bf2f((u16)(v.x >> 16));
    f[2] = bf2f((u16)(v.y & 0xffff)); f[3] = bf2f((u16)(v.y >> 16));
    f[4] = bf2f((u16)(v.z & 0xffff)); f[5] = bf2f((u16)(v.z >> 16));
    f[6] = bf2f((u16)(v.w & 0xffff)); f[7] = bf2f((u16)(v.w >> 16));
}
__device__ __forceinline__ float ld1(const void* p, size_t i, int F){
    return F ? ((const float*)p)[i] : bf2f(((const u16*)p)[i]);
}
__device__ __forceinline__ void ld8(const void* p, size_t i, int F, float* f){
    if (F){
        const float* fp = (const float*)p + i;
        float4 a = *(const float4*)fp;
        float4 b = *(const float4*)(fp + 4);
        f[0]=a.x; f[1]=a.y; f[2]=a.z; f[3]=a.w;
        f[4]=b.x; f[5]=b.y; f[6]=b.z; f[7]=b.w;
    } else {
        uint4 v = *(const uint4*)((const u16*)p + i);
        unpack8(v, f);
    }
}
__device__ __forceinline__ float clampf(float x, float lo, float hi){
    return fminf(fmaxf(x, lo), hi);
}
// per-block dtype detect: wave 0 probes 128 u16 of pred_size (values in [0.2,1.5])
__device__ __forceinline__ int detectF(const void* pred_size, int* Fs){
    int tid = threadIdx.x;
    if (tid < 64){
        const u16* ps = (const u16*)pred_size;
        u16 v0 = ps[tid], v1 = ps[tid + 64];
        int cc = ((v0 >= 0x3000 && v0 < 0x4100) ? 1 : 0)
               + ((v1 >= 0x3000 && v1 < 0x4100) ? 1 : 0);
        #pragma unroll
        for (int off = 32; off > 0; off >>= 1) cc += __shfl_xor(cc, off);
        if (tid == 0) *Fs = (cc >= 120) ? 0 : 1;   // 0 = bf16, 1 = f32
    }
    __syncthreads();
    return *Fs;
}

// ================= D1: prep (mask/tgt/needlist/alist) + proj =================
__device__ void prep_fn(char* smem,
        const void* obj, const void* gtc, const void* gts,
        const void* pc_, const void* ps_, int F,
        u8* mask, float* cnt_part, u8* tgt, float* tcnt_part,
        int* needcnt_part, int* needlist, int* acnt_part, int* alist,
        int b0, int P, int L, int bblk)
{
    int tid = threadIdx.x;
    int ntile = P / 256;
    int b = bblk / ntile, ct = bblk % ntile;
    int p = ct * 256 + tid;

    float* gtb = (float*)smem;            // L*8
    float* tl  = gtb + (size_t)L * 8;     // L
    float* red = tl + L;                  // 256
    int*   wb  = (int*)(red + 256);       // 4
    int*   wb2 = wb + 4;                  // 4

    if (tid < L){
        float gmn[3], gmx[3], gss[3];
        for (int i = 0; i < 3; i++){
            size_t gi = ((size_t)(b0 + b) * L + tid) * 3 + i;
            float gc  = ld1(gtc, gi, F);
            float gsv = ld1(gts, gi, F) + 0.01f;
            gmn[i] = gc - 0.5f * gsv; gmx[i] = gc + 0.5f * gsv; gss[i] = gsv;
        }
        float* r = &gtb[tid * 8];
        r[0] = gmn[0]; r[1] = gmn[1]; r[2] = gmn[2];
        r[3] = gmx[0]; r[4] = gmx[1]; r[5] = gmx[2];
        r[6] = gss[0] * gss[1] * gss[2];
        tl[tid] = 0.f;
    }
    __syncthreads();

    size_t ob = ((size_t)(b0 + b) * P + p) * 2;
    float s0 = ld1(obj, ob, F), s1 = ld1(obj, ob + 1, F);
    u8 m = (s1 > s0) ? 1 : 0;
    mask[(size_t)b * P + p] = m;

    size_t pb = ((size_t)(b0 + b) * P + p) * 3;
    float pl[3], ph[3], volp = 1.f;
    for (int i = 0; i < 3; i++){
        float pcv = ld1(pc_, pb + i, F), psv = ld1(ps_, pb + i, F);
        pl[i] = pcv - 0.5f * psv; ph[i] = pcv + 0.5f * psv; volp *= psv;
    }
    bool any = false;
    for (int l = 0; l < L; l++){
        float* r = &gtb[l * 8];
        float inter = 1.f;
        for (int i = 0; i < 3; i++){
            float mn = fmaxf(r[i],     pl[i]);
            float mx = fminf(r[3 + i], ph[i]);
            inter *= fmaxf(mx - mn, 0.f);
        }
        float iou = inter / (r[6] + volp - inter + 1e-7f);
        u8 t = (iou > 0.25f && m) ? 1 : 0;
        tgt[((size_t)b * L + l) * P + p] = t;
        if (t){ any = true; atomicAdd(&tl[l], 1.f); }
    }

    int wid = tid >> 6, lane = tid & 63;
    u64 bal  = __ballot(any);
    u64 bal2 = __ballot(m != 0);
    if (lane == 0){ wb[wid] = __popcll(bal); wb2[wid] = __popcll(bal2); }
    red[tid] = (float)m;
    __syncthreads();
    if (tid == 0){
        int s = 0;
        for (int w = 0; w < 4; w++){ int cn = wb[w];  wb[w]  = s; s += cn; }
        needcnt_part[b * 4 + ct] = s;
        s = 0;
        for (int w = 0; w < 4; w++){ int cn = wb2[w]; wb2[w] = s; s += cn; }
        acnt_part[b * 4 + ct] = s;
    }
    __syncthreads();
    if (any){
        int rank = __popcll(bal & ((1ULL << lane) - 1ULL));
        needlist[(size_t)b * P + ct * 256 + wb[wid] + rank] = p;
    }
    if (m){
        int rank = __popcll(bal2 & ((1ULL << lane) - 1ULL));
        alist[(size_t)b * P + ct * 256 + wb2[wid] + rank] = p;
    }
    for (int st = 128; st > 0; st >>= 1){
        if (tid < st) red[tid] += red[tid + st];
        __syncthreads();
    }
    if (tid == 0) cnt_part[b * 4 + ct] = red[0];
    if (tid < L)  tcnt_part[(size_t)(b * 4 + ct) * L + tid] = tl[tid];
}

__device__ void proj_fn(char* smem,
        const void* __restrict__ X, const void* __restrict__ W, int F,
        u16* __restrict__ outb, int row0, int rowoff, int nrows)
{
    int tid = threadIdx.x;
    u16* Ws = (u16*)smem;
    u16* Xs = (u16*)(smem + 32768);

    for (int i = 0; i < 8; i++){
        int cid = tid + i * 256;
        int r = cid >> 4, cc = cid & 15;
        float f[8];
        ld8(W, (size_t)r * H128 + cc * 8, F, f);
        u16* dst = &Ws[r * H128 + ((cc ^ (r & 15)) * 8)];
        #pragma unroll
        for (int j = 0; j < 8; j++) dst[j] = f2bf(f[j]);
    }
    for (int i = 0; i < 4; i++){
        int cid = tid + i * 256;
        int r = cid >> 4, cc = cid & 15;
        int row = row0 + r;
        float f[8];
        if (row < nrows){
            ld8(X, (size_t)(rowoff + row) * H128 + cc * 8, F, f);
        } else {
            for (int j = 0; j < 8; j++) f[j] = 0.f;
        }
        u16* dst = &Xs[r * H128 + ((cc ^ (r & 15)) * 8)];
        #pragma unroll
        for (int j = 0; j < 8; j++) dst[j] = f2bf(f[j]);
    }
    __syncthreads();

    int w = tid >> 6, lane = tid & 63;
    int quad = lane >> 4, mrow = lane & 15;

    short8_t af[4];
    int arow = w * 16 + mrow;
    #pragma unroll
    for (int kt = 0; kt < 4; kt++){
        int chunk = kt * 4 + quad;
        af[kt] = *(const short8_t*)&Xs[arow * H128 + ((chunk ^ mrow) * 8)];
    }

    f32x4_t acc[8];
    #pragma unroll
    for (int ntl = 0; ntl < 8; ntl++) acc[ntl] = (f32x4_t){0.f, 0.f, 0.f, 0.f};
    #pragma unroll
    for (int ntl = 0; ntl < 8; ntl++){
        int n = ntl * 16 + mrow;
        #pragma unroll
        for (int kt = 0; kt < 4; kt++){
            int chunk = kt * 4 + quad;
            short8_t bf = *(const short8_t*)&Ws[n * H128 + ((chunk ^ mrow) * 8)];
            acc[ntl] = __builtin_amdgcn_mfma_f32_16x16x32_bf16(af[kt], bf, acc[ntl], 0, 0, 0);
        }
    }

    float ss[4] = {0.f, 0.f, 0.f, 0.f};
    #pragma unroll
    for (int ntl = 0; ntl < 8; ntl++)
        #pragma unroll
        for (int reg = 0; reg < 4; reg++) ss[reg] += acc[ntl][reg] * acc[ntl][reg];
    #pragma unroll
    for (int off = 1; off <= 8; off <<= 1)
        #pragma unroll
        for (int reg = 0; reg < 4; reg++) ss[reg] += __shfl_xor(ss[reg], off);
    float rn[4];
    #pragma unroll
    for (int reg = 0; reg < 4; reg++) rn[reg] = 1.0f / fmaxf(sqrtf(ss[reg]), 1e-12f);

    #pragma unroll
    for (int reg = 0; reg < 4; reg++){
        int row = row0 + w * 16 + quad * 4 + reg;
        if (row < nrows){
            #pragma unroll
            for (int ntl = 0; ntl < 8; ntl++){
                int col = ntl * 16 + mrow;
                outb[(size_t)row * H128 + col] = f2bf(acc[ntl][reg] * rn[reg]);
            }
        }
    }
}

__global__ void __launch_bounds__(256) k_main1(
        const void* __restrict__ obj, const void* __restrict__ gtc, const void* __restrict__ gts,
        const void* __restrict__ pc_, const void* __restrict__ ps_,
        const void* __restrict__ bbox, const void* __restrict__ lang,
        const void* __restrict__ Wp, const void* __restrict__ Wpi, const void* __restrict__ Wt,
        u8* __restrict__ mask, float* __restrict__ cnt_part, u8* __restrict__ tgt,
        float* __restrict__ tcnt_part, int* __restrict__ needcnt_part, int* __restrict__ needlist,
        int* __restrict__ acnt_part, int* __restrict__ alist,
        u16* __restrict__ boxl, u16* __restrict__ boxi, u16* __restrict__ text,
        float* __restrict__ accf, u32* __restrict__ ctrs, int* __restrict__ flagp,
        int chunk_idx, int first,
        int nprep, int nb1, int b0, int P, int L, int nrows_bp, int nrows_t)
{
    __shared__ __align__(16) char smem[49152];
    __shared__ int Fs;
    int F = detectF(ps_, &Fs);
    int blk = blockIdx.x;
    if (blk == 0 && threadIdx.x == 0){
        ctrs[chunk_idx] = 0u;
        *flagp = F;
        if (first){ accf[0] = 0.f; accf[1] = 0.f; }
    }
    if (blk < nprep){
        prep_fn(smem, obj, gtc, gts, pc_, ps_, F, mask, cnt_part, tgt, tcnt_part,
                needcnt_part, needlist, acnt_part, alist, b0, P, L, blk);
        return;
    }
    blk -= nprep;
    if (blk < nb1)
        proj_fn(smem, bbox, Wp,  F, boxl, blk * 64,             b0 * P, nrows_bp);
    else if (blk < 2 * nb1)
        proj_fn(smem, bbox, Wpi, F, boxi, (blk - nb1) * 64,     b0 * P, nrows_bp);
    else
        proj_fn(smem, lang, Wt,  F, text, (blk - 2 * nb1) * 64, b0 * L, nrows_t);
}

// ================= D2: lang-GEMM + lse-GEMM (partial-buffer writes) =================
__device__ void lang_fn(char* smem,
        const u16* __restrict__ text, const u16* __restrict__ boxl,
        const u8* __restrict__ mask, const u8* __restrict__ tgt,
        float* __restrict__ sexp_part, float* __restrict__ sdot_part, int P, int L, int bblk)
{
    int nct = P >> 7;
    int b = bblk / nct, ct = bblk % nct;
    int p0 = ct * 128;
    int tid = threadIdx.x;

    u16* As = (u16*)smem;                 // 8192
    u16* Bs = (u16*)(smem + 8192);        // 32768
    u8*  Ts = (u8*)(smem + 40960);        // 4096
    u8*  mk = (u8*)(smem + 45056);        // 128

    for (int i = 0; i < 2; i++){
        int cid = tid + i * 256;
        int r = cid >> 4, cc = cid & 15;
        uint4 v = *(const uint4*)&text[((size_t)b * L + r) * H128 + cc * 8];
        *(uint4*)&As[r * H128 + ((cc ^ (r & 15)) * 8)] = v;
    }
    for (int i = 0; i < 8; i++){
        int cid = tid + i * 256;
        int r = cid >> 4, cc = cid & 15;
        uint4 v = *(const uint4*)&boxl[((size_t)b * P + p0 + r) * H128 + cc * 8];
        *(uint4*)&Bs[r * H128 + ((cc ^ (r & 15)) * 8)] = v;
    }
    {
        int l = tid >> 3, seg = tid & 7;
        uint4 v = *(const uint4*)&tgt[((size_t)b * L + l) * P + p0 + seg * 16];
        *(uint4*)&Ts[l * 128 + seg * 16] = v;
    }
    if (tid < 128) mk[tid] = mask[(size_t)b * P + p0 + tid];
    __syncthreads();

    int w = tid >> 6, lane = tid & 63;
    int quad = lane >> 4, mrow = lane & 15;
    int mt = w & 1, ch = w >> 1;

    short8_t af[4];
    #pragma unroll
    for (int kt = 0; kt < 4; kt++){
        int chunk = kt * 4 + quad;
        af[kt] = *(const short8_t*)&As[(mt * 16 + mrow) * H128 + ((chunk ^ mrow) * 8)];
    }

    float se[4] = {0.f, 0.f, 0.f, 0.f};
    float sd[4] = {0.f, 0.f, 0.f, 0.f};
    #pragma unroll
    for (int nt = 0; nt < 4; nt++){
        int cl = ch * 64 + nt * 16 + mrow;
        f32x4_t acc = (f32x4_t){0.f, 0.f, 0.f, 0.f};
        #pragma unroll
        for (int kt = 0; kt < 4; kt++){
            int chunk = kt * 4 + quad;
            short8_t bf = *(const short8_t*)&Bs[cl * H128 + ((chunk ^ mrow) * 8)];
            acc = __builtin_amdgcn_mfma_f32_16x16x32_bf16(af[kt], bf, acc, 0, 0, 0);
        }
        float m = mk[cl] ? 1.f : 0.f;
        #pragma unroll
        for (int reg = 0; reg < 4; reg++){
            int l = mt * 16 + quad * 4 + reg;
            float d = acc[reg];
            se[reg] += m * __expf(d);
            if (m != 0.f && Ts[l * 128 + cl]) sd[reg] += d;
        }
    }
    #pragma unroll
    for (int off = 1; off <= 8; off <<= 1)
        #pragma unroll
        for (int reg = 0; reg < 4; reg++){
            se[reg] += __shfl_xor(se[reg], off);
            sd[reg] += __shfl_xor(sd[reg], off);
        }
    if (mrow == 0){
        #pragma unroll
        for (int reg = 0; reg < 4; reg++){
            int l = mt * 16 + quad * 4 + reg;
            size_t idx = (size_t)(b * L + l) * 16 + ct * 2 + ch;
            sexp_part[idx] = se[reg];
            sdot_part[idx] = sd[reg];
        }
    }
}

__device__ void lse_fn(char* smem,
        const u16* __restrict__ boxi,
        const int* __restrict__ needcnt_part, const int* __restrict__ needlist,
        const int* __restrict__ acnt_part, const int* __restrict__ alist,
        float* __restrict__ lse_part, int P, int bblk)
{
    int b = bblk >> 3, ctA = bblk & 7;
    int prefA[5], preN[5];
    prefA[0] = 0; preN[0] = 0;
    for (int j = 0; j < 4; j++){
        prefA[j + 1] = prefA[j] + acnt_part[b * 4 + j];
        preN[j + 1]  = preN[j]  + needcnt_part[b * 4 + j];
    }
    int acnt = prefA[4], ncnt = preN[4];
    if (ctA * 128 >= acnt || ncnt <= 0) return;
    int tid = threadIdx.x;

    u16* Bs = (u16*)smem;               // 32768
    u8*  mk = (u8*)(smem + 32768);      // 128

    for (int i = 0; i < 8; i++){
        int cid = tid + i * 256;
        int r = cid >> 4, cc = cid & 15;
        int aq = ctA * 128 + r;
        uint4 v = {0, 0, 0, 0};
        if (aq < acnt){
            int j = (aq >= prefA[1]) + (aq >= prefA[2]) + (aq >= prefA[3]);
            int cp = alist[(size_t)b * P + j * 256 + (aq - prefA[j])];
            v = *(const uint4*)&boxi[((size_t)b * P + cp) * H128 + cc * 8];
        }
        *(uint4*)&Bs[r * H128 + ((cc ^ (r & 15)) * 8)] = v;
    }
    if (tid < 128) mk[tid] = (ctA * 128 + tid < acnt) ? 1 : 0;
    __syncthreads();

    int w = tid >> 6, lane = tid & 63;
    int quad = lane >> 4, mrow = lane & 15;
    int nrt = (ncnt + 15) >> 4;

    for (int rt = w; rt < nrt; rt += 4){
        int i = rt * 16 + mrow;
        int ic = (i < ncnt) ? i : (ncnt - 1);
        int j = (ic >= preN[1]) + (ic >= preN[2]) + (ic >= preN[3]);
        int prow = needlist[(size_t)b * P + j * 256 + (ic - preN[j])];
        const u16* ab = &boxi[((size_t)b * P + prow) * H128];
        short8_t af[4];
        #pragma unroll
        for (int kt = 0; kt < 4; kt++)
            af[kt] = *(const short8_t*)&ab[(kt * 4 + quad) * 8];

        float se[4] = {0.f, 0.f, 0.f, 0.f};
        #pragma unroll
        for (int nt = 0; nt < 8; nt++){
            int cl = nt * 16 + mrow;
            f32x4_t acc = (f32x4_t){0.f, 0.f, 0.f, 0.f};
            #pragma unroll
            for (int kt = 0; kt < 4; kt++){
                int chunk = kt * 4 + quad;
                short8_t bf = *(const short8_t*)&Bs[cl * H128 + ((chunk ^ mrow) * 8)];
                acc = __builtin_amdgcn_mfma_f32_16x16x32_bf16(af[kt], bf, acc, 0, 0, 0);
            }
            float m = mk[cl] ? 1.f : 0.f;
            #pragma unroll
            for (int reg = 0; reg < 4; reg++) se[reg] += m * __expf(acc[reg]);
        }
        #pragma unroll
        for (int off = 1; off <= 8; off <<= 1)
            #pragma unroll
            for (int reg = 0; reg < 4; reg++) se[reg] += __shfl_xor(se[reg], off);
        if (mrow == 0){
            #pragma unroll
            for (int reg = 0; reg < 4; reg++){
                int i2 = rt * 16 + quad * 4 + reg;
                if (i2 < ncnt){
                    int j2 = (i2 >= preN[1]) + (i2 >= preN[2]) + (i2 >= preN[3]);
                    int pr2 = needlist[(size_t)b * P + j2 * 256 + (i2 - preN[j2])];
                    lse_part[((size_t)b * P + pr2) * 8 + ctA] = se[reg];
                }
            }
        }
    }
}

__global__ void __launch_bounds__(256) k_main2(
        const u16* __restrict__ text, const u16* __restrict__ boxl, const u16* __restrict__ boxi,
        const u8* __restrict__ mask, const u8* __restrict__ tgt,
        const int* __restrict__ needcnt_part, const int* __restrict__ needlist,
        const int* __restrict__ acnt_part, const int* __restrict__ alist,
        float* __restrict__ sexp_part, float* __restrict__ sdot_part,
        float* __restrict__ lse_part, int nlang, int P, int L)
{
    __shared__ __align__(16) char smem[45184];
    int blk = blockIdx.x;
    if (blk < nlang) lang_fn(smem, text, boxl, mask, tgt, sexp_part, sdot_part, P, L, blk);
    else             lse_fn(smem, boxi, needcnt_part, needlist, acnt_part, alist,
                            lse_part, P, blk - nlang);
}

// ================= D3: per-(b,l) losses + counter-elected finalize =================
__global__ void __launch_bounds__(256) k_main3(
        const u16* __restrict__ boxi, const u8* __restrict__ tgt,
        const float* __restrict__ lse_part, const float* __restrict__ cnt_part,
        const float* __restrict__ tcnt_part, const float* __restrict__ sexp_part,
        const float* __restrict__ sdot_part, const int* __restrict__ acnt_part,
        const int* __restrict__ lang_raw, float* __restrict__ loss_part,
        float* __restrict__ accf, u32* __restrict__ ctr, const int* __restrict__ flagp,
        void* __restrict__ out, float invB, int is_last, int B, int b0, int P, int L)
{
    int blk = blockIdx.x, b = blk / L, l = blk % L, tid = threadIdx.x;
    bool is64 = (B >= 8) && lang_raw[1] == 0 && lang_raw[3] == 0 &&
                lang_raw[5] == 0 && lang_raw[7] == 0;
    int lniv = is64 ? lang_raw[2 * (b0 + b)] : lang_raw[b0 + b];
    float tf = tcnt_part[(size_t)(b * 4 + 0) * L + l] + tcnt_part[(size_t)(b * 4 + 1) * L + l]
             + tcnt_part[(size_t)(b * 4 + 2) * L + l] + tcnt_part[(size_t)(b * 4 + 3) * L + l];
    bool active = (l < lniv) && (tf > 0.f);

    __shared__ int mem[1024];
    __shared__ int wbase[4];
    __shared__ int total;
    __shared__ float redu[256];
    __shared__ float redu2[256];
    __shared__ float Ufin;
    __shared__ int lastf;

    float lang_loss = 0.f, iou_loss = 0.f;
    if (active){
        float c1 = fmaxf(cnt_part[b * 4] + cnt_part[b * 4 + 1] +
                         cnt_part[b * 4 + 2] + cnt_part[b * 4 + 3], 1.f);
        int acnt = acnt_part[b * 4] + acnt_part[b * 4 + 1] +
                   acnt_part[b * 4 + 2] + acnt_part[b * 4 + 3];
        int nact = (acnt + 127) >> 7;

        int wid = tid >> 6, lane = tid & 63;
        if (tid == 0) total = 0;
        __syncthreads();
        for (int k = 0; k < P / 256; k++){
            int p = tid + k * 256;
            bool hit = (tgt[((size_t)b * L + l) * P + p] != 0);
            u64 bal = __ballot(hit);
            if (lane == 0) wbase[wid] = __popcll(bal);
            __syncthreads();
            if (tid == 0){
                int s = total;
                for (int w = 0; w < 4; w++){ int c = wbase[w]; wbase[w] = s; s += c; }
                total = s;
            }
            __syncthreads();
            if (hit){
                int rank = __popcll(bal & ((1ULL << lane) - 1ULL));
                mem[wbase[wid] + rank] = p;
            }
            __syncthreads();
        }
        int t = total;

        float U = 0.f;
        for (int i = tid; i < t; i += 256){
            const float* lp = &lse_part[((size_t)b * P + mem[i]) * 8];
            float s = 0.f;
            for (int ctA = 0; ctA < nact; ctA++) s += lp[ctA];
            U += logf(fmaxf(s, 1e-30f));
        }
        redu[tid] = U; __syncthreads();
        for (int st = 128; st > 0; st >>= 1){
            if (tid < st) redu[tid] += redu[tid + st];
            __syncthreads();
        }
        if (tid == 0) Ufin = redu[0];
        __syncthreads();

        {
            int h = tid & 127, half = tid >> 7;
            float vh = 0.f;
            for (int i = half; i < t; i += 2)
                vh += bf2f(boxi[((size_t)b * P + mem[i]) * H128 + h]);
            redu[tid] = vh;
        }
        __syncthreads();
        if (tid < 128){
            float v = redu[tid] + redu[tid + 128];
            redu[tid] = v * v;
        }
        __syncthreads();
        for (int st = 64; st > 0; st >>= 1){
            if (tid < st) redu[tid] += redu[tid + st];
            __syncthreads();
        }
        if (tid == 0){
            float sexp = 0.f, sdot = 0.f;
            const float* ep = &sexp_part[(size_t)(b * L + l) * 16];
            const float* dp = &sdot_part[(size_t)(b * L + l) * 16];
            for (int k = 0; k < 16; k++){ sexp += ep[k]; sdot += dp[k]; }
            float LSE = logf(fmaxf(sexp, 1e-30f));
            lang_loss = clampf(0.5f * (tf * LSE - sdot) / c1, -1e5f, 1e5f);
            iou_loss  = clampf(((float)t * Ufin - redu[0]) / (c1 * c1), -1e5f, 1e5f);
        }
    }

    if (tid == 0){
        loss_part[blk] = lang_loss;
        loss_part[gridDim.x + blk] = iou_loss;
        __threadfence();
        u32 old = atomicAdd(ctr, 1u);
        lastf = (old == (u32)(gridDim.x - 1)) ? 1 : 0;
    }
    __syncthreads();
    if (lastf){
        __threadfence();
        float suml = 0.f, sumi = 0.f;
        for (int i = tid; i < (int)gridDim.x; i += 256){
            suml += loss_part[i];
            sumi += loss_part[gridDim.x + i];
        }
        redu[tid] = suml; redu2[tid] = sumi;
        __syncthreads();
        for (int st = 128; st > 0; st >>= 1){
            if (tid < st){ redu[tid] += redu[tid + st]; redu2[tid] += redu2[tid + st]; }
            __syncthreads();
        }
        if (tid == 0){
            accf[0] += redu[0];
            accf[1] += redu2[0];
            if (is_last){
                float a  = clampf(accf[0] * invB, -1e6f, 1e6f);
                float bb = clampf(accf[1] * invB, -1e6f, 1e6f);
                if (*flagp){
                    ((float*)out)[0] = a; ((float*)out)[1] = bb;
                } else {
                    ((u16*)out)[0] = f2bf(a); ((u16*)out)[1] = f2bf(bb);
                }
            }
        }
    }
}

extern "C" void kernel_launch(void* const* d_in, const int* in_sizes, int n_in,
                              void* d_out, int out_size, void* d_ws, size_t ws_size,
                              hipStream_t stream)
{
    const void* pred_center = d_in[0];
    const void* pred_size   = d_in[1];
    const void* bbox        = d_in[2];
    const void* gtc         = d_in[3];
    const void* gts         = d_in[4];
    const void* lang        = d_in[5];
    const void* obj         = d_in[6];
    const void* Wt          = d_in[7];
    const void* Wp          = d_in[8];
    const void* Wpi         = d_in[9];
    const int*  lang_raw    = (const int*)d_in[10];

    int B = in_sizes[10];
    int P = in_sizes[0] / (3 * B);
    int L = in_sizes[3] / (3 * B);
    (void)n_in; (void)out_size;

    char* w = (char*)d_ws;
    float* accf  = (float*)w;
    int*   flagp = (int*)(w + 64);
    u32*   ctrs  = (u32*)(w + 128);      // up to 64 chunk counters
    char*  chunk_base = w + 512;
    size_t chunk_avail = (ws_size > 512) ? ws_size - 512 : 0;

    size_t per_b = (size_t)P                      // mask
                 + 64                             // cnt/acnt/needcnt parts
                 + (size_t)4 * L * 4              // tcnt_part
                 + (size_t)L * 16 * 4 * 2         // sexp/sdot parts
                 + (size_t)L * P                  // tgt
                 + (size_t)P * 4 * 2              // needlist + alist
                 + (size_t)P * 8 * 4              // lse_part
                 + (size_t)P * H128 * 2 * 2       // boxl + boxi
                 + (size_t)L * H128 * 2           // text
                 + (size_t)L * 8;                 // loss_part
    size_t slop = 20 * 256;
    int C = B;
    if ((size_t)B * per_b + slop > chunk_avail){
        size_t av = (chunk_avail > slop) ? chunk_avail - slop : 0;
        C = (int)(av / per_b);
        if (C < 1) C = 1;
        if (C > B) C = B;
    }

    int chunk_idx = 0;
    for (int b0 = 0; b0 < B; b0 += C, chunk_idx++){
        int c = (B - b0 < C) ? (B - b0) : C;

        size_t off = 0;
        auto carve = [&](size_t bytes) -> void* {
            void* p = chunk_base + off;
            off = (off + bytes + 255) & ~(size_t)255;
            return p;
        };
        u8*    mask      = (u8*)   carve((size_t)c * P);
        float* cnt_part  = (float*)carve((size_t)c * 4 * 4);
        int*   acnt_part = (int*)  carve((size_t)c * 4 * 4);
        int*   ncnt_part = (int*)  carve((size_t)c * 4 * 4);
        float* tcnt_part = (float*)carve((size_t)c * 4 * L * 4);
        float* sexp_part = (float*)carve((size_t)c * L * 16 * 4);
        float* sdot_part = (float*)carve((size_t)c * L * 16 * 4);
        u8*    tgtb      = (u8*)   carve((size_t)c * L * P);
        int*   needlist  = (int*)  carve((size_t)c * P * 4);
        int*   alist     = (int*)  carve((size_t)c * P * 4);
        float* lse_part  = (float*)carve((size_t)c * P * 8 * 4);
        u16*   boxl      = (u16*)  carve((size_t)c * P * H128 * 2);
        u16*   boxi      = (u16*)  carve((size_t)c * P * H128 * 2);
        u16*   text      = (u16*)  carve((size_t)c * L * H128 * 2);
        float* loss_part = (float*)carve((size_t)c * L * 8);

        int is_last = (b0 + c >= B) ? 1 : 0;
        int nprep = c * (P / 256);
        int nb1 = (c * P + 63) / 64;
        int nbt = (c * L + 63) / 64;

        k_main1<<<nprep + 2 * nb1 + nbt, 256, 0, stream>>>(
            obj, gtc, gts, pred_center, pred_size, bbox, lang, Wp, Wpi, Wt,
            mask, cnt_part, tgtb, tcnt_part, ncnt_part, needlist, acnt_part, alist,
            boxl, boxi, text, accf, ctrs, flagp, chunk_idx, (b0 == 0) ? 1 : 0,
            nprep, nb1, b0, P, L, c * P, c * L);

        int nlang = c * (P / 128);
        k_main2<<<nlang + c * 8, 256, 0, stream>>>(
            text, boxl, boxi, mask, tgtb, ncnt_part, needlist, acnt_part, alist,
            sexp_part, sdot_part, lse_part, nlang, P, L);

        k_main3<<<c * L, 256, 0, stream>>>(
            boxi, tgtb, lse_part, cnt_part, tcnt_part, sexp_part, sdot_part,
            acnt_part, lang_raw, loss_part, accf, &ctrs[chunk_idx], flagp, d_out,
            1.0f / (float)B, is_last, B, b0, P, L);
    }
}